// Round 2
// baseline (988.130 us; speedup 1.0000x reference)
//
#include <hip/hip_runtime.h>
#include <hip/hip_bf16.h>

// ---------------------------------------------------------------------------
// EnhancedGNN: 2-layer GCN (PyG GCNConv semantics) + linear head + sigmoid.
//   deg[d] = 1 + #incoming edges; dis = rsqrt(deg)
//   layer: agg[d] = sum_e dis[s]*dis[d] * (xW)[s]  +  (1/deg[d])*(xW)[d] + b
//   h1 = relu(layer1(x)); h2 = layer2(h1); out = sigmoid(h2 @ Wl + bl)
// Baseline strategy: atomicAdd scatter per edge (64 lanes = 64 features).
// ---------------------------------------------------------------------------

__global__ void deg_init_k(float* __restrict__ deg, int n) {
    int i = blockIdx.x * blockDim.x + threadIdx.x;
    if (i < n) deg[i] = 1.0f;
}

__global__ void deg_edges_k(const int* __restrict__ dst, float* __restrict__ deg, int E) {
    int e = blockIdx.x * blockDim.x + threadIdx.x;
    if (e < E) atomicAdd(&deg[dst[e]], 1.0f);
}

__global__ void dis_k(float* __restrict__ deg, int n) {
    int i = blockIdx.x * blockDim.x + threadIdx.x;
    if (i < n) deg[i] = rsqrtf(deg[i]);   // in-place: deg -> dis
}

// Y[row, j] = sum_k X[row, k] * W[k, j], lane j of the wave owns output j.
// W (K x 64) staged in LDS; x row elements are wave-uniform loads (HW broadcast).
template <int K, bool RELU_IN>
__global__ __launch_bounds__(256) void gemm_rows_k(
    const float* __restrict__ X, const float* __restrict__ W,
    float* __restrict__ Y, int n) {
    __shared__ float Ws[K * 64];
    for (int t = threadIdx.x; t < K * 64; t += blockDim.x) Ws[t] = W[t];
    __syncthreads();

    int wave   = (int)((blockIdx.x * blockDim.x + threadIdx.x) >> 6);
    int lane   = threadIdx.x & 63;
    int nwaves = (int)((gridDim.x * blockDim.x) >> 6);

    for (int row = wave; row < n; row += nwaves) {
        const float* xr = X + (size_t)row * K;
        float acc = 0.f;
        #pragma unroll 4
        for (int k = 0; k < K; k += 4) {
            float4 xv = *reinterpret_cast<const float4*>(xr + k);  // uniform addr
            if (RELU_IN) {
                xv.x = fmaxf(xv.x, 0.f); xv.y = fmaxf(xv.y, 0.f);
                xv.z = fmaxf(xv.z, 0.f); xv.w = fmaxf(xv.w, 0.f);
            }
            acc = fmaf(xv.x, Ws[(k + 0) * 64 + lane], acc);
            acc = fmaf(xv.y, Ws[(k + 1) * 64 + lane], acc);
            acc = fmaf(xv.z, Ws[(k + 2) * 64 + lane], acc);
            acc = fmaf(xv.w, Ws[(k + 3) * 64 + lane], acc);
        }
        Y[(size_t)row * 64 + lane] = acc;
    }
}

// agg[i,:] = dis[i]^2 * t[i,:] + b[:]   (self-loop term + bias)
__global__ void init_agg_k(const float* __restrict__ t, const float* __restrict__ dis,
                           const float* __restrict__ b, float* __restrict__ agg, int n) {
    int idx = blockIdx.x * blockDim.x + threadIdx.x;
    if (idx >= n * 64) return;
    int i = idx >> 6, j = idx & 63;
    float ds = dis[i];
    agg[idx] = ds * ds * t[idx] + b[j];
}

// One wave per edge: agg[dst,:] += dis[src]*dis[dst] * t[src,:]
__global__ __launch_bounds__(256) void agg_edges_k(
    const int* __restrict__ src, const int* __restrict__ dst,
    const float* __restrict__ dis, const float* __restrict__ t,
    float* __restrict__ agg, int E) {
    int e    = (int)((blockIdx.x * blockDim.x + threadIdx.x) >> 6);
    int lane = threadIdx.x & 63;
    if (e >= E) return;
    int s = src[e], d = dst[e];
    float w = dis[s] * dis[d];
    atomicAdd(&agg[(size_t)d * 64 + lane], w * t[(size_t)s * 64 + lane]);
}

// out[i] = sigmoid( dot(agg[i,:], Wl) + bl ) ; one wave per node
__global__ __launch_bounds__(256) void final_k(
    const float* __restrict__ agg, const float* __restrict__ Wl,
    const float* __restrict__ bl, float* __restrict__ out, int n) {
    int node = (int)((blockIdx.x * blockDim.x + threadIdx.x) >> 6);
    int lane = threadIdx.x & 63;
    if (node >= n) return;
    float v = agg[(size_t)node * 64 + lane] * Wl[lane];
    #pragma unroll
    for (int m = 32; m >= 1; m >>= 1) v += __shfl_xor(v, m);
    if (lane == 0) out[node] = 1.f / (1.f + expf(-(v + bl[0])));
}

extern "C" void kernel_launch(void* const* d_in, const int* in_sizes, int n_in,
                              void* d_out, int out_size, void* d_ws, size_t ws_size,
                              hipStream_t stream) {
    const float* x  = (const float*)d_in[0];
    const int*   ei = (const int*)d_in[1];
    const float* W1 = (const float*)d_in[2];
    const float* b1 = (const float*)d_in[3];
    const float* W2 = (const float*)d_in[4];
    const float* b2 = (const float*)d_in[5];
    const float* Wl = (const float*)d_in[6];
    const float* bl = (const float*)d_in[7];
    float* out = (float*)d_out;

    const int n = in_sizes[0] / 128;      // 100000
    const int E = in_sizes[1] / 2;        // 1600000
    const int* src = ei;
    const int* dst = ei + E;

    char* ws = (char*)d_ws;
    float* dis  = (float*)ws;                                   // n floats (deg -> dis)
    size_t off  = ((size_t)n * sizeof(float) + 511) & ~(size_t)511;
    float* bufA = (float*)(ws + off);                           // n*64 floats
    float* bufB = bufA + (size_t)n * 64;                        // n*64 floats

    const int B = 256;
    dim3 blk(B);

    // degree -> dis
    deg_init_k<<<(n + B - 1) / B, blk, 0, stream>>>(dis, n);
    deg_edges_k<<<(E + B - 1) / B, blk, 0, stream>>>(dst, dis, E);
    dis_k<<<(n + B - 1) / B, blk, 0, stream>>>(dis, n);

    // layer 1: bufA = x @ W1 ; bufB = aggregate + bias (relu deferred into GEMM2)
    gemm_rows_k<128, false><<<2048, blk, 0, stream>>>(x, W1, bufA, n);
    init_agg_k<<<(n * 64 + B - 1) / B, blk, 0, stream>>>(bufA, dis, b1, bufB, n);
    agg_edges_k<<<(E + 3) / 4, blk, 0, stream>>>(src, dst, dis, bufA, bufB, E);

    // layer 2: bufA = relu(bufB) @ W2 ; bufB = aggregate + bias
    gemm_rows_k<64, true><<<2048, blk, 0, stream>>>(bufB, W2, bufA, n);
    init_agg_k<<<(n * 64 + B - 1) / B, blk, 0, stream>>>(bufA, dis, b2, bufB, n);
    agg_edges_k<<<(E + 3) / 4, blk, 0, stream>>>(src, dst, dis, bufA, bufB, E);

    // head
    final_k<<<(n + 3) / 4, blk, 0, stream>>>(bufB, Wl, bl, out, n);
}

// Round 3
// 523.136 us; speedup vs baseline: 1.8889x; 1.8889x over previous
//
#include <hip/hip_runtime.h>
#include <hip/hip_bf16.h>

// ---------------------------------------------------------------------------
// EnhancedGNN: 2-layer GCN + linear head + sigmoid.
// R2 strategy: build CSR (by dst) once per launch, then gather-accumulate in
// registers (no float atomics). Fusions: bias+self-loop into gather; ReLU into
// layer-1 gather output; Wl/bl/sigmoid head into layer-2 gather.
// Fallback to the R1 atomic-scatter path if ws_size is too small for CSR.
// ---------------------------------------------------------------------------

#define SCAN_CHUNK 1024

// ---------------- CSR build ----------------

__global__ void hist_k(const int* __restrict__ dst, int* __restrict__ hist, int E) {
    int e = blockIdx.x * blockDim.x + threadIdx.x;
    if (e < E) atomicAdd(&hist[dst[e]], 1);
}

// dis[i] = rsqrt(1 + in_degree)
__global__ void dis_from_hist_k(const int* __restrict__ hist, float* __restrict__ dis, int n) {
    int i = blockIdx.x * blockDim.x + threadIdx.x;
    if (i < n) dis[i] = rsqrtf((float)hist[i] + 1.0f);
}

__global__ void scan_partial_k(const int* __restrict__ hist, int* __restrict__ bsum, int n) {
    __shared__ int sdata[256];
    int base = blockIdx.x * SCAN_CHUNK;
    int t = threadIdx.x;
    int s = 0;
    for (int i = t; i < SCAN_CHUNK; i += 256) {
        int idx = base + i;
        s += (idx < n) ? hist[idx] : 0;
    }
    sdata[t] = s; __syncthreads();
    for (int m = 128; m > 0; m >>= 1) {
        if (t < m) sdata[t] += sdata[t + m];
        __syncthreads();
    }
    if (t == 0) bsum[blockIdx.x] = sdata[0];
}

__global__ void scan_bsum_k(int* __restrict__ bsum, int nb) {
    if (threadIdx.x == 0 && blockIdx.x == 0) {
        int run = 0;
        for (int i = 0; i < nb; ++i) { int v = bsum[i]; bsum[i] = run; run += v; }
    }
}

__global__ void scan_final_k(const int* __restrict__ hist, const int* __restrict__ bsum,
                             int* __restrict__ row_start, int* __restrict__ cursor, int n) {
    __shared__ int tsum[256];
    int base = blockIdx.x * SCAN_CHUNK;
    int t = threadIdx.x;
    int idx0 = base + t * 4;
    int v[4]; int s = 0;
    #pragma unroll
    for (int k = 0; k < 4; ++k) { int idx = idx0 + k; v[k] = (idx < n) ? hist[idx] : 0; s += v[k]; }
    tsum[t] = s; __syncthreads();
    #pragma unroll
    for (int off = 1; off < 256; off <<= 1) {
        int val = (t >= off) ? tsum[t - off] : 0;
        __syncthreads();
        tsum[t] += val;
        __syncthreads();
    }
    int excl = (t > 0 ? tsum[t - 1] : 0) + bsum[blockIdx.x];
    #pragma unroll
    for (int k = 0; k < 4; ++k) {
        int idx = idx0 + k;
        if (idx < n) { row_start[idx] = excl; cursor[idx] = excl; }
        excl += v[k];
        if (idx == n - 1) row_start[n] = excl;   // total = E
    }
}

__global__ void scatter_k(const int* __restrict__ src, const int* __restrict__ dst,
                          int* __restrict__ cursor, int* __restrict__ csr_src, int E) {
    int e = blockIdx.x * blockDim.x + threadIdx.x;
    if (e < E) {
        int pos = atomicAdd(&cursor[dst[e]], 1);
        csr_src[pos] = src[e];
    }
}

// ---------------- dense row GEMM (lane j owns output feature j) ----------------

template <int K, bool RELU_IN>
__global__ __launch_bounds__(256) void gemm_rows_k(
    const float* __restrict__ X, const float* __restrict__ W,
    float* __restrict__ Y, int n) {
    __shared__ float Ws[K * 64];
    for (int t = threadIdx.x; t < K * 64; t += blockDim.x) Ws[t] = W[t];
    __syncthreads();

    int wave   = (int)((blockIdx.x * blockDim.x + threadIdx.x) >> 6);
    int lane   = threadIdx.x & 63;
    int nwaves = (int)((gridDim.x * blockDim.x) >> 6);

    for (int row = wave; row < n; row += nwaves) {
        const float* xr = X + (size_t)row * K;
        float acc = 0.f;
        #pragma unroll 4
        for (int k = 0; k < K; k += 4) {
            float4 xv = *reinterpret_cast<const float4*>(xr + k);  // wave-uniform
            if (RELU_IN) {
                xv.x = fmaxf(xv.x, 0.f); xv.y = fmaxf(xv.y, 0.f);
                xv.z = fmaxf(xv.z, 0.f); xv.w = fmaxf(xv.w, 0.f);
            }
            acc = fmaf(xv.x, Ws[(k + 0) * 64 + lane], acc);
            acc = fmaf(xv.y, Ws[(k + 1) * 64 + lane], acc);
            acc = fmaf(xv.z, Ws[(k + 2) * 64 + lane], acc);
            acc = fmaf(xv.w, Ws[(k + 3) * 64 + lane], acc);
        }
        Y[(size_t)row * 64 + lane] = acc;
    }
}

// ---------------- CSR gather aggregation (one wave per node) ----------------
// MODE 0: out = relu(agg + b)        (layer 1)
// MODE 1: out = sigmoid(dot(agg + b, Wl) + bl)   (layer 2 + head fused)
template <int MODE>
__global__ __launch_bounds__(256) void gather_k(
    const int* __restrict__ row_start, const int* __restrict__ csr_src,
    const float* __restrict__ dis, const float* __restrict__ t,
    const float* __restrict__ b, const float* __restrict__ Wl,
    const float* __restrict__ bl, float* __restrict__ outbuf, int n) {
    int node = (int)((blockIdx.x * blockDim.x + threadIdx.x) >> 6);
    int lane = threadIdx.x & 63;
    if (node >= n) return;
    int beg = row_start[node], end = row_start[node + 1];
    float dd = dis[node];
    float acc = dd * dd * t[(size_t)node * 64 + lane] + b[lane];

    int j = beg;
    for (; j + 3 < end; j += 4) {
        int s0 = csr_src[j], s1 = csr_src[j + 1], s2 = csr_src[j + 2], s3 = csr_src[j + 3];
        float w0 = dis[s0] * dd, w1 = dis[s1] * dd, w2 = dis[s2] * dd, w3 = dis[s3] * dd;
        acc = fmaf(w0, t[(size_t)s0 * 64 + lane], acc);
        acc = fmaf(w1, t[(size_t)s1 * 64 + lane], acc);
        acc = fmaf(w2, t[(size_t)s2 * 64 + lane], acc);
        acc = fmaf(w3, t[(size_t)s3 * 64 + lane], acc);
    }
    for (; j < end; ++j) {
        int s = csr_src[j];
        acc = fmaf(dis[s] * dd, t[(size_t)s * 64 + lane], acc);
    }

    if (MODE == 0) {
        outbuf[(size_t)node * 64 + lane] = fmaxf(acc, 0.f);
    } else {
        float v = acc * Wl[lane];
        #pragma unroll
        for (int m = 32; m >= 1; m >>= 1) v += __shfl_xor(v, m);
        if (lane == 0) outbuf[node] = 1.f / (1.f + expf(-(v + bl[0])));
    }
}

// ---------------- R1 fallback kernels (atomic scatter path) ----------------

__global__ void deg_init_k(float* __restrict__ deg, int n) {
    int i = blockIdx.x * blockDim.x + threadIdx.x;
    if (i < n) deg[i] = 1.0f;
}
__global__ void deg_edges_k(const int* __restrict__ dst, float* __restrict__ deg, int E) {
    int e = blockIdx.x * blockDim.x + threadIdx.x;
    if (e < E) atomicAdd(&deg[dst[e]], 1.0f);
}
__global__ void dis_k(float* __restrict__ deg, int n) {
    int i = blockIdx.x * blockDim.x + threadIdx.x;
    if (i < n) deg[i] = rsqrtf(deg[i]);
}
__global__ void init_agg_k(const float* __restrict__ t, const float* __restrict__ dis,
                           const float* __restrict__ b, float* __restrict__ agg, int n) {
    int idx = blockIdx.x * blockDim.x + threadIdx.x;
    if (idx >= n * 64) return;
    int i = idx >> 6, jj = idx & 63;
    float ds = dis[i];
    agg[idx] = ds * ds * t[idx] + b[jj];
}
__global__ __launch_bounds__(256) void agg_edges_k(
    const int* __restrict__ src, const int* __restrict__ dst,
    const float* __restrict__ dis, const float* __restrict__ t,
    float* __restrict__ agg, int E) {
    int e    = (int)((blockIdx.x * blockDim.x + threadIdx.x) >> 6);
    int lane = threadIdx.x & 63;
    if (e >= E) return;
    int s = src[e], d = dst[e];
    float w = dis[s] * dis[d];
    atomicAdd(&agg[(size_t)d * 64 + lane], w * t[(size_t)s * 64 + lane]);
}
__global__ __launch_bounds__(256) void final_k(
    const float* __restrict__ agg, const float* __restrict__ Wl,
    const float* __restrict__ bl, float* __restrict__ out, int n) {
    int node = (int)((blockIdx.x * blockDim.x + threadIdx.x) >> 6);
    int lane = threadIdx.x & 63;
    if (node >= n) return;
    float v = agg[(size_t)node * 64 + lane] * Wl[lane];
    #pragma unroll
    for (int m = 32; m >= 1; m >>= 1) v += __shfl_xor(v, m);
    if (lane == 0) out[node] = 1.f / (1.f + expf(-(v + bl[0])));
}

// ---------------------------------------------------------------------------

extern "C" void kernel_launch(void* const* d_in, const int* in_sizes, int n_in,
                              void* d_out, int out_size, void* d_ws, size_t ws_size,
                              hipStream_t stream) {
    const float* x  = (const float*)d_in[0];
    const int*   ei = (const int*)d_in[1];
    const float* W1 = (const float*)d_in[2];
    const float* b1 = (const float*)d_in[3];
    const float* W2 = (const float*)d_in[4];
    const float* b2 = (const float*)d_in[5];
    const float* Wl = (const float*)d_in[6];
    const float* bl = (const float*)d_in[7];
    float* out = (float*)d_out;

    const int n = in_sizes[0] / 128;      // 100000
    const int E = in_sizes[1] / 2;        // 1600000
    const int* src = ei;
    const int* dst = ei + E;

    const int B = 256;
    dim3 blk(B);

    auto align512 = [](size_t v) { return (v + 511) & ~(size_t)511; };

    // CSR-path workspace layout
    char* ws = (char*)d_ws;
    size_t off = 0;
    float* dis      = (float*)(ws + off); off = align512(off + (size_t)n * 4);
    int*   hist     = (int*)  (ws + off); off = align512(off + (size_t)n * 4);
    int*   row_st   = (int*)  (ws + off); off = align512(off + (size_t)(n + 1) * 4);
    int*   cursor   = (int*)  (ws + off); off = align512(off + (size_t)n * 4);
    int*   csr_src  = (int*)  (ws + off); off = align512(off + (size_t)E * 4);
    float* bufA     = (float*)(ws + off); off += (size_t)n * 64 * 4;
    float* bufB     = (float*)(ws + off); off += (size_t)n * 64 * 4;
    size_t need_csr = off;

    if (ws_size >= need_csr) {
        // ---- CSR build ----
        hipMemsetAsync(hist, 0, (size_t)n * 4, stream);
        hist_k<<<(E + B - 1) / B, blk, 0, stream>>>(dst, hist, E);
        dis_from_hist_k<<<(n + B - 1) / B, blk, 0, stream>>>(hist, dis, n);
        int nb = (n + SCAN_CHUNK - 1) / SCAN_CHUNK;
        scan_partial_k<<<nb, blk, 0, stream>>>(hist, cursor /*bsum scratch*/, n);
        // NOTE: bsum needs its own storage; reuse tail of cursor is unsafe since
        // scan_final writes cursor. Use a small dedicated region: hist is still
        // needed by scan_final, row_st not yet written -> use row_st tail? No:
        // keep it simple, bsum lives in the last nb ints of csr_src (csr not yet
        // written; scatter happens after scan completes).
        int* bsum = csr_src + (size_t)E - nb - 1;
        scan_partial_k<<<nb, blk, 0, stream>>>(hist, bsum, n);
        scan_bsum_k<<<1, 64, 0, stream>>>(bsum, nb);
        scan_final_k<<<nb, blk, 0, stream>>>(hist, bsum, row_st, cursor, n);
        scatter_k<<<(E + B - 1) / B, blk, 0, stream>>>(src, dst, cursor, csr_src, E);

        // ---- layer 1 ----
        gemm_rows_k<128, false><<<2048, blk, 0, stream>>>(x, W1, bufA, n);
        gather_k<0><<<((size_t)n * 64 + B - 1) / B, blk, 0, stream>>>(
            row_st, csr_src, dis, bufA, b1, Wl, bl, bufB, n);

        // ---- layer 2 + head ----
        gemm_rows_k<64, false><<<2048, blk, 0, stream>>>(bufB, W2, bufA, n);
        gather_k<1><<<((size_t)n * 64 + B - 1) / B, blk, 0, stream>>>(
            row_st, csr_src, dis, bufA, b2, Wl, bl, out, n);
    } else {
        // ---- R1 fallback: atomic scatter ----
        size_t o2 = 0;
        float* dis2 = (float*)(ws + o2); o2 = align512(o2 + (size_t)n * 4);
        float* bA   = (float*)(ws + o2); o2 += (size_t)n * 64 * 4;
        float* bB   = (float*)(ws + o2);

        deg_init_k<<<(n + B - 1) / B, blk, 0, stream>>>(dis2, n);
        deg_edges_k<<<(E + B - 1) / B, blk, 0, stream>>>(dst, dis2, E);
        dis_k<<<(n + B - 1) / B, blk, 0, stream>>>(dis2, n);

        gemm_rows_k<128, false><<<2048, blk, 0, stream>>>(x, W1, bA, n);
        init_agg_k<<<((size_t)n * 64 + B - 1) / B, blk, 0, stream>>>(bA, dis2, b1, bB, n);
        agg_edges_k<<<(E + 3) / 4, blk, 0, stream>>>(src, dst, dis2, bA, bB, E);

        gemm_rows_k<64, true><<<2048, blk, 0, stream>>>(bB, W2, bA, n);
        init_agg_k<<<((size_t)n * 64 + B - 1) / B, blk, 0, stream>>>(bA, dis2, b2, bB, n);
        agg_edges_k<<<(E + 3) / 4, blk, 0, stream>>>(src, dst, dis2, bA, bB, E);

        final_k<<<(n + 3) / 4, blk, 0, stream>>>(bB, Wl, bl, out, n);
    }
}

// Round 4
// 475.834 us; speedup vs baseline: 2.0766x; 1.0994x over previous
//
#include <hip/hip_runtime.h>
#include <hip/hip_bf16.h>

// ---------------------------------------------------------------------------
// EnhancedGNN: 2-layer GCN + linear head + sigmoid.
// R3: (a) 4-rows-per-wave GEMM (amortize LDS reads over 4 FMAs),
//     (b) two-phase bucketed CSR scatter (LDS hist partition -> place),
//     (c) drop dead scan launch. Gather kernels unchanged.
// ---------------------------------------------------------------------------

#define SCAN_CHUNK 1024
#define EPB 4096      // edges per partition block
#define NBMAX 512     // max buckets (n/256)

// ---------------- CSR build ----------------

__global__ void hist_k(const int* __restrict__ dst, int* __restrict__ hist, int E) {
    int e = blockIdx.x * blockDim.x + threadIdx.x;
    if (e < E) atomicAdd(&hist[dst[e]], 1);
}

__global__ void dis_from_hist_k(const int* __restrict__ hist, float* __restrict__ dis, int n) {
    int i = blockIdx.x * blockDim.x + threadIdx.x;
    if (i < n) dis[i] = rsqrtf((float)hist[i] + 1.0f);
}

__global__ void scan_partial_k(const int* __restrict__ hist, int* __restrict__ bsum, int n) {
    __shared__ int sdata[256];
    int base = blockIdx.x * SCAN_CHUNK;
    int t = threadIdx.x;
    int s = 0;
    for (int i = t; i < SCAN_CHUNK; i += 256) {
        int idx = base + i;
        s += (idx < n) ? hist[idx] : 0;
    }
    sdata[t] = s; __syncthreads();
    for (int m = 128; m > 0; m >>= 1) {
        if (t < m) sdata[t] += sdata[t + m];
        __syncthreads();
    }
    if (t == 0) bsum[blockIdx.x] = sdata[0];
}

__global__ void scan_bsum_k(int* __restrict__ bsum, int nb) {
    if (threadIdx.x == 0 && blockIdx.x == 0) {
        int run = 0;
        for (int i = 0; i < nb; ++i) { int v = bsum[i]; bsum[i] = run; run += v; }
    }
}

__global__ void scan_final_k(const int* __restrict__ hist, const int* __restrict__ bsum,
                             int* __restrict__ row_start, int* __restrict__ cursor, int n) {
    __shared__ int tsum[256];
    int base = blockIdx.x * SCAN_CHUNK;
    int t = threadIdx.x;
    int idx0 = base + t * 4;
    int v[4]; int s = 0;
    #pragma unroll
    for (int k = 0; k < 4; ++k) { int idx = idx0 + k; v[k] = (idx < n) ? hist[idx] : 0; s += v[k]; }
    tsum[t] = s; __syncthreads();
    #pragma unroll
    for (int off = 1; off < 256; off <<= 1) {
        int val = (t >= off) ? tsum[t - off] : 0;
        __syncthreads();
        tsum[t] += val;
        __syncthreads();
    }
    int excl = (t > 0 ? tsum[t - 1] : 0) + bsum[blockIdx.x];
    #pragma unroll
    for (int k = 0; k < 4; ++k) {
        int idx = idx0 + k;
        if (idx < n) { row_start[idx] = excl; cursor[idx] = excl; }
        excl += v[k];
        if (idx == n - 1) row_start[n] = excl;   // total = E
    }
}

// bucket_cur[b] = csr offset where bucket b (nodes [b*256,(b+1)*256)) begins
__global__ void bucket_init_k(const int* __restrict__ row_start, int* __restrict__ bucket_cur, int nbuckets) {
    int b = blockIdx.x * blockDim.x + threadIdx.x;
    if (b < nbuckets) bucket_cur[b] = row_start[b << 8];
}

// Phase 1: partition edges into dst-bucket-clustered staging (src,dst) pairs.
__global__ __launch_bounds__(256) void partition_k(
    const int* __restrict__ src, const int* __restrict__ dst,
    int* __restrict__ bucket_cur, int2* __restrict__ stage, int E, int nbuckets) {
    __shared__ int ls[EPB];
    __shared__ int ld[EPB];
    __shared__ int lhist[NBMAX];
    __shared__ int lbase[NBMAX];
    int e0 = blockIdx.x * EPB;
    int cnt = min(EPB, E - e0);
    int t = threadIdx.x;
    for (int i = t; i < cnt; i += 256) { ls[i] = src[e0 + i]; ld[i] = dst[e0 + i]; }
    for (int b = t; b < nbuckets; b += 256) lhist[b] = 0;
    __syncthreads();
    for (int i = t; i < cnt; i += 256) atomicAdd(&lhist[ld[i] >> 8], 1);
    __syncthreads();
    for (int b = t; b < nbuckets; b += 256) {
        int c = lhist[b];
        lbase[b] = (c > 0) ? atomicAdd(&bucket_cur[b], c) : 0;
        lhist[b] = 0;
    }
    __syncthreads();
    for (int i = t; i < cnt; i += 256) {
        int b  = ld[i] >> 8;
        int off = atomicAdd(&lhist[b], 1);
        stage[lbase[b] + off] = make_int2(ls[i], ld[i]);
    }
}

// Phase 2: final placement; dst values arrive bucket-clustered -> csr writes
// and cursor atomics confined to small hot windows.
__global__ void place_k(const int2* __restrict__ stage, int* __restrict__ cursor,
                        int* __restrict__ csr_src, int E) {
    int e = blockIdx.x * blockDim.x + threadIdx.x;
    if (e < E) {
        int2 p = stage[e];
        int pos = atomicAdd(&cursor[p.y], 1);
        csr_src[pos] = p.x;
    }
}

// Fallback single-phase scatter (used only if nbuckets > NBMAX).
__global__ void scatter_k(const int* __restrict__ src, const int* __restrict__ dst,
                          int* __restrict__ cursor, int* __restrict__ csr_src, int E) {
    int e = blockIdx.x * blockDim.x + threadIdx.x;
    if (e < E) {
        int pos = atomicAdd(&cursor[dst[e]], 1);
        csr_src[pos] = src[e];
    }
}

// ---------------- dense row GEMM, 4 rows per wave ----------------
// One LDS read of Ws[k][lane] feeds 4 FMAs (one per row) -> FMA-bound.
template <int K>
__global__ __launch_bounds__(256) void gemm_rows4_k(
    const float* __restrict__ X, const float* __restrict__ W,
    float* __restrict__ Y, int n) {
    __shared__ float Ws[K * 64];
    for (int t = threadIdx.x; t < K * 64; t += blockDim.x) Ws[t] = W[t];
    __syncthreads();

    int wave   = (int)((blockIdx.x * blockDim.x + threadIdx.x) >> 6);
    int lane   = threadIdx.x & 63;
    int nwaves = (int)((gridDim.x * blockDim.x) >> 6);
    int ngroups = (n + 3) >> 2;

    for (int g = wave; g < ngroups; g += nwaves) {
        int r0 = g << 2;
        const float* x0 = X + (size_t)r0 * K;
        if (r0 + 3 < n) {
            float acc0 = 0.f, acc1 = 0.f, acc2 = 0.f, acc3 = 0.f;
            #pragma unroll 2
            for (int k = 0; k < K; k += 4) {
                float4 a0 = *reinterpret_cast<const float4*>(x0 + k);
                float4 a1 = *reinterpret_cast<const float4*>(x0 + K + k);
                float4 a2 = *reinterpret_cast<const float4*>(x0 + 2 * K + k);
                float4 a3 = *reinterpret_cast<const float4*>(x0 + 3 * K + k);
                float w0 = Ws[(k + 0) * 64 + lane];
                float w1 = Ws[(k + 1) * 64 + lane];
                float w2 = Ws[(k + 2) * 64 + lane];
                float w3 = Ws[(k + 3) * 64 + lane];
                acc0 = fmaf(a0.x, w0, acc0); acc0 = fmaf(a0.y, w1, acc0);
                acc0 = fmaf(a0.z, w2, acc0); acc0 = fmaf(a0.w, w3, acc0);
                acc1 = fmaf(a1.x, w0, acc1); acc1 = fmaf(a1.y, w1, acc1);
                acc1 = fmaf(a1.z, w2, acc1); acc1 = fmaf(a1.w, w3, acc1);
                acc2 = fmaf(a2.x, w0, acc2); acc2 = fmaf(a2.y, w1, acc2);
                acc2 = fmaf(a2.z, w2, acc2); acc2 = fmaf(a2.w, w3, acc2);
                acc3 = fmaf(a3.x, w0, acc3); acc3 = fmaf(a3.y, w1, acc3);
                acc3 = fmaf(a3.z, w2, acc3); acc3 = fmaf(a3.w, w3, acc3);
            }
            float* y0 = Y + (size_t)r0 * 64 + lane;
            y0[0] = acc0; y0[64] = acc1; y0[128] = acc2; y0[192] = acc3;
        } else {
            for (int r = r0; r < n; ++r) {
                const float* xr = X + (size_t)r * K;
                float acc = 0.f;
                for (int k = 0; k < K; k += 4) {
                    float4 a = *reinterpret_cast<const float4*>(xr + k);
                    acc = fmaf(a.x, Ws[(k + 0) * 64 + lane], acc);
                    acc = fmaf(a.y, Ws[(k + 1) * 64 + lane], acc);
                    acc = fmaf(a.z, Ws[(k + 2) * 64 + lane], acc);
                    acc = fmaf(a.w, Ws[(k + 3) * 64 + lane], acc);
                }
                Y[(size_t)r * 64 + lane] = acc;
            }
        }
    }
}

// ---------------- CSR gather aggregation (one wave per node) ----------------
// MODE 0: out = relu(agg + b)                    (layer 1)
// MODE 1: out = sigmoid(dot(agg + b, Wl) + bl)   (layer 2 + head fused)
template <int MODE>
__global__ __launch_bounds__(256) void gather_k(
    const int* __restrict__ row_start, const int* __restrict__ csr_src,
    const float* __restrict__ dis, const float* __restrict__ t,
    const float* __restrict__ b, const float* __restrict__ Wl,
    const float* __restrict__ bl, float* __restrict__ outbuf, int n) {
    int node = (int)((blockIdx.x * blockDim.x + threadIdx.x) >> 6);
    int lane = threadIdx.x & 63;
    if (node >= n) return;
    int beg = row_start[node], end = row_start[node + 1];
    float dd = dis[node];
    float acc = dd * dd * t[(size_t)node * 64 + lane] + b[lane];

    int j = beg;
    for (; j + 3 < end; j += 4) {
        int s0 = csr_src[j], s1 = csr_src[j + 1], s2 = csr_src[j + 2], s3 = csr_src[j + 3];
        float w0 = dis[s0] * dd, w1 = dis[s1] * dd, w2 = dis[s2] * dd, w3 = dis[s3] * dd;
        acc = fmaf(w0, t[(size_t)s0 * 64 + lane], acc);
        acc = fmaf(w1, t[(size_t)s1 * 64 + lane], acc);
        acc = fmaf(w2, t[(size_t)s2 * 64 + lane], acc);
        acc = fmaf(w3, t[(size_t)s3 * 64 + lane], acc);
    }
    for (; j < end; ++j) {
        int s = csr_src[j];
        acc = fmaf(dis[s] * dd, t[(size_t)s * 64 + lane], acc);
    }

    if (MODE == 0) {
        outbuf[(size_t)node * 64 + lane] = fmaxf(acc, 0.f);
    } else {
        float v = acc * Wl[lane];
        #pragma unroll
        for (int m = 32; m >= 1; m >>= 1) v += __shfl_xor(v, m);
        if (lane == 0) outbuf[node] = 1.f / (1.f + expf(-(v + bl[0])));
    }
}

// ---------------- R1 fallback kernels (only if ws too small) ----------------

__global__ void deg_init_k(float* __restrict__ deg, int n) {
    int i = blockIdx.x * blockDim.x + threadIdx.x;
    if (i < n) deg[i] = 1.0f;
}
__global__ void deg_edges_k(const int* __restrict__ dst, float* __restrict__ deg, int E) {
    int e = blockIdx.x * blockDim.x + threadIdx.x;
    if (e < E) atomicAdd(&deg[dst[e]], 1.0f);
}
__global__ void dis_k(float* __restrict__ deg, int n) {
    int i = blockIdx.x * blockDim.x + threadIdx.x;
    if (i < n) deg[i] = rsqrtf(deg[i]);
}
__global__ void init_agg_k(const float* __restrict__ t, const float* __restrict__ dis,
                           const float* __restrict__ b, float* __restrict__ agg, int n) {
    int idx = blockIdx.x * blockDim.x + threadIdx.x;
    if (idx >= n * 64) return;
    int i = idx >> 6, jj = idx & 63;
    float ds = dis[i];
    agg[idx] = ds * ds * t[idx] + b[jj];
}
__global__ __launch_bounds__(256) void agg_edges_k(
    const int* __restrict__ src, const int* __restrict__ dst,
    const float* __restrict__ dis, const float* __restrict__ t,
    float* __restrict__ agg, int E) {
    int e    = (int)((blockIdx.x * blockDim.x + threadIdx.x) >> 6);
    int lane = threadIdx.x & 63;
    if (e >= E) return;
    int s = src[e], d = dst[e];
    float w = dis[s] * dis[d];
    atomicAdd(&agg[(size_t)d * 64 + lane], w * t[(size_t)s * 64 + lane]);
}
__global__ __launch_bounds__(256) void final_k(
    const float* __restrict__ agg, const float* __restrict__ Wl,
    const float* __restrict__ bl, float* __restrict__ out, int n) {
    int node = (int)((blockIdx.x * blockDim.x + threadIdx.x) >> 6);
    int lane = threadIdx.x & 63;
    if (node >= n) return;
    float v = agg[(size_t)node * 64 + lane] * Wl[lane];
    #pragma unroll
    for (int m = 32; m >= 1; m >>= 1) v += __shfl_xor(v, m);
    if (lane == 0) out[node] = 1.f / (1.f + expf(-(v + bl[0])));
}

// ---------------------------------------------------------------------------

extern "C" void kernel_launch(void* const* d_in, const int* in_sizes, int n_in,
                              void* d_out, int out_size, void* d_ws, size_t ws_size,
                              hipStream_t stream) {
    const float* x  = (const float*)d_in[0];
    const int*   ei = (const int*)d_in[1];
    const float* W1 = (const float*)d_in[2];
    const float* b1 = (const float*)d_in[3];
    const float* W2 = (const float*)d_in[4];
    const float* b2 = (const float*)d_in[5];
    const float* Wl = (const float*)d_in[6];
    const float* bl = (const float*)d_in[7];
    float* out = (float*)d_out;

    const int n = in_sizes[0] / 128;      // 100000
    const int E = in_sizes[1] / 2;        // 1600000
    const int* src = ei;
    const int* dst = ei + E;

    const int B = 256;
    dim3 blk(B);
    auto align512 = [](size_t v) { return (v + 511) & ~(size_t)511; };

    // workspace layout
    char* ws = (char*)d_ws;
    size_t off = 0;
    float* dis     = (float*)(ws + off); off = align512(off + (size_t)n * 4);
    int*   hist    = (int*)  (ws + off); off = align512(off + (size_t)n * 4);
    int*   row_st  = (int*)  (ws + off); off = align512(off + (size_t)(n + 1) * 4);
    int*   cursor  = (int*)  (ws + off); off = align512(off + (size_t)n * 4);
    int*   bcur    = (int*)  (ws + off); off = align512(off + (size_t)NBMAX * 4);
    int*   csr_src = (int*)  (ws + off); off = align512(off + (size_t)E * 4);
    float* bufA    = (float*)(ws + off); off += (size_t)n * 64 * 4;
    float* bufB    = (float*)(ws + off); off += (size_t)n * 64 * 4;
    size_t need_csr = off;

    if (ws_size >= need_csr) {
        const int nbuckets = (n + 255) >> 8;

        // ---- CSR build ----
        hipMemsetAsync(hist, 0, (size_t)n * 4, stream);
        hist_k<<<(E + B - 1) / B, blk, 0, stream>>>(dst, hist, E);
        dis_from_hist_k<<<(n + B - 1) / B, blk, 0, stream>>>(hist, dis, n);
        int nb = (n + SCAN_CHUNK - 1) / SCAN_CHUNK;
        int* bsum = csr_src + (size_t)E - nb - 1;   // scratch; consumed before csr writes
        scan_partial_k<<<nb, blk, 0, stream>>>(hist, bsum, n);
        scan_bsum_k<<<1, 64, 0, stream>>>(bsum, nb);
        scan_final_k<<<nb, blk, 0, stream>>>(hist, bsum, row_st, cursor, n);

        if (nbuckets <= NBMAX) {
            // bucketed two-phase scatter; stage aliases bufA (dead until gemm1)
            int2* stage = (int2*)bufA;
            bucket_init_k<<<(nbuckets + B - 1) / B, blk, 0, stream>>>(row_st, bcur, nbuckets);
            partition_k<<<(E + EPB - 1) / EPB, blk, 0, stream>>>(src, dst, bcur, stage, E, nbuckets);
            place_k<<<(E + B - 1) / B, blk, 0, stream>>>(stage, cursor, csr_src, E);
        } else {
            scatter_k<<<(E + B - 1) / B, blk, 0, stream>>>(src, dst, cursor, csr_src, E);
        }

        // ---- layer 1 ----
        gemm_rows4_k<128><<<1024, blk, 0, stream>>>(x, W1, bufA, n);
        gather_k<0><<<((size_t)n * 64 + B - 1) / B, blk, 0, stream>>>(
            row_st, csr_src, dis, bufA, b1, Wl, bl, bufB, n);

        // ---- layer 2 + head ----
        gemm_rows4_k<64><<<1024, blk, 0, stream>>>(bufB, W2, bufA, n);
        gather_k<1><<<((size_t)n * 64 + B - 1) / B, blk, 0, stream>>>(
            row_st, csr_src, dis, bufA, b2, Wl, bl, out, n);
    } else {
        // ---- R1 fallback: atomic scatter ----
        size_t o2 = 0;
        float* dis2 = (float*)(ws + o2); o2 = align512(o2 + (size_t)n * 4);
        float* bA   = (float*)(ws + o2); o2 += (size_t)n * 64 * 4;
        float* bB   = (float*)(ws + o2);

        deg_init_k<<<(n + B - 1) / B, blk, 0, stream>>>(dis2, n);
        deg_edges_k<<<(E + B - 1) / B, blk, 0, stream>>>(dst, dis2, E);
        dis_k<<<(n + B - 1) / B, blk, 0, stream>>>(dis2, n);

        gemm_rows4_k<128><<<1024, blk, 0, stream>>>(x, W1, bA, n);
        init_agg_k<<<((size_t)n * 64 + B - 1) / B, blk, 0, stream>>>(bA, dis2, b1, bB, n);
        agg_edges_k<<<(E + 3) / 4, blk, 0, stream>>>(src, dst, dis2, bA, bB, E);

        // fallback path needs relu before gemm2: reuse init_agg trick is wrong;
        // simply apply relu inside gather-less path via a tiny kernel-free trick:
        // gemm_rows4_k has no RELU_IN, so do relu in init_agg consumer instead.
        // (bB holds pre-relu layer-1 output; relu it in-place)
        // reuse dis_k slot: write a lambda-style relu kernel
        // NOTE: simple elementwise relu:
        {
            // relu in place over n*64
            auto grid = ((size_t)n * 64 + B - 1) / B;
            // defined below as relu_k
            extern __global__ void relu_k(float*, long long);
            relu_k<<<grid, blk, 0, stream>>>(bB, (long long)n * 64);
        }
        gemm_rows4_k<64><<<1024, blk, 0, stream>>>(bB, W2, bA, n);
        init_agg_k<<<((size_t)n * 64 + B - 1) / B, blk, 0, stream>>>(bA, dis2, b2, bB, n);
        agg_edges_k<<<(E + 3) / 4, blk, 0, stream>>>(src, dst, dis2, bA, bB, E);

        final_k<<<(n + 3) / 4, blk, 0, stream>>>(bB, Wl, bl, out, n);
    }
}

__global__ void relu_k(float* __restrict__ p, long long m) {
    long long i = (long long)blockIdx.x * blockDim.x + threadIdx.x;
    if (i < m) p[i] = fmaxf(p[i], 0.f);
}

// Round 5
// 327.414 us; speedup vs baseline: 3.0180x; 1.4533x over previous
//
#include <hip/hip_runtime.h>
#include <hip/hip_bf16.h>

// ---------------------------------------------------------------------------
// EnhancedGNN: 2-layer GCN + linear head + sigmoid.
// R5: bf16 MFMA GEMMs (16x16x32), W pre-packed to B-fragment layout, in-reg
//     fp32->bf16 conversion for A; gather1 emits bf16 to feed gemm2.
//     CSR build (bucketed two-phase scatter) unchanged from R3.
// ---------------------------------------------------------------------------

#define SCAN_CHUNK 1024
#define EPB 4096      // edges per partition block
#define NBMAX 512     // max buckets (n/256)

typedef __attribute__((ext_vector_type(8))) short bf16x8;
typedef __attribute__((ext_vector_type(4))) float f32x4;

__device__ __forceinline__ unsigned short f2b(float f) {   // fp32->bf16 RNE
    unsigned u = __builtin_bit_cast(unsigned, f);
    u += 0x7fffu + ((u >> 16) & 1u);
    return (unsigned short)(u >> 16);
}
__device__ __forceinline__ float b2f(unsigned short h) {
    unsigned u = (unsigned)h << 16;
    return __builtin_bit_cast(float, u);
}

// ---------------- CSR build ----------------

__global__ void hist_k(const int* __restrict__ dst, int* __restrict__ hist, int E) {
    int e = blockIdx.x * blockDim.x + threadIdx.x;
    if (e < E) atomicAdd(&hist[dst[e]], 1);
}

__global__ void dis_from_hist_k(const int* __restrict__ hist, float* __restrict__ dis, int n) {
    int i = blockIdx.x * blockDim.x + threadIdx.x;
    if (i < n) dis[i] = rsqrtf((float)hist[i] + 1.0f);
}

__global__ void scan_partial_k(const int* __restrict__ hist, int* __restrict__ bsum, int n) {
    __shared__ int sdata[256];
    int base = blockIdx.x * SCAN_CHUNK;
    int t = threadIdx.x;
    int s = 0;
    for (int i = t; i < SCAN_CHUNK; i += 256) {
        int idx = base + i;
        s += (idx < n) ? hist[idx] : 0;
    }
    sdata[t] = s; __syncthreads();
    for (int m = 128; m > 0; m >>= 1) {
        if (t < m) sdata[t] += sdata[t + m];
        __syncthreads();
    }
    if (t == 0) bsum[blockIdx.x] = sdata[0];
}

__global__ void scan_bsum_k(int* __restrict__ bsum, int nb) {
    if (threadIdx.x == 0 && blockIdx.x == 0) {
        int run = 0;
        for (int i = 0; i < nb; ++i) { int v = bsum[i]; bsum[i] = run; run += v; }
    }
}

__global__ void scan_final_k(const int* __restrict__ hist, const int* __restrict__ bsum,
                             int* __restrict__ row_start, int* __restrict__ cursor, int n) {
    __shared__ int tsum[256];
    int base = blockIdx.x * SCAN_CHUNK;
    int t = threadIdx.x;
    int idx0 = base + t * 4;
    int v[4]; int s = 0;
    #pragma unroll
    for (int k = 0; k < 4; ++k) { int idx = idx0 + k; v[k] = (idx < n) ? hist[idx] : 0; s += v[k]; }
    tsum[t] = s; __syncthreads();
    #pragma unroll
    for (int off = 1; off < 256; off <<= 1) {
        int val = (t >= off) ? tsum[t - off] : 0;
        __syncthreads();
        tsum[t] += val;
        __syncthreads();
    }
    int excl = (t > 0 ? tsum[t - 1] : 0) + bsum[blockIdx.x];
    #pragma unroll
    for (int k = 0; k < 4; ++k) {
        int idx = idx0 + k;
        if (idx < n) { row_start[idx] = excl; cursor[idx] = excl; }
        excl += v[k];
        if (idx == n - 1) row_start[n] = excl;   // total = E
    }
}

__global__ void bucket_init_k(const int* __restrict__ row_start, int* __restrict__ bucket_cur, int nbuckets) {
    int b = blockIdx.x * blockDim.x + threadIdx.x;
    if (b < nbuckets) bucket_cur[b] = row_start[b << 8];
}

__global__ __launch_bounds__(256) void partition_k(
    const int* __restrict__ src, const int* __restrict__ dst,
    int* __restrict__ bucket_cur, int2* __restrict__ stage, int E, int nbuckets) {
    __shared__ int ls[EPB];
    __shared__ int ld[EPB];
    __shared__ int lhist[NBMAX];
    __shared__ int lbase[NBMAX];
    int e0 = blockIdx.x * EPB;
    int cnt = min(EPB, E - e0);
    int t = threadIdx.x;
    for (int i = t; i < cnt; i += 256) { ls[i] = src[e0 + i]; ld[i] = dst[e0 + i]; }
    for (int b = t; b < nbuckets; b += 256) lhist[b] = 0;
    __syncthreads();
    for (int i = t; i < cnt; i += 256) atomicAdd(&lhist[ld[i] >> 8], 1);
    __syncthreads();
    for (int b = t; b < nbuckets; b += 256) {
        int c = lhist[b];
        lbase[b] = (c > 0) ? atomicAdd(&bucket_cur[b], c) : 0;
        lhist[b] = 0;
    }
    __syncthreads();
    for (int i = t; i < cnt; i += 256) {
        int b  = ld[i] >> 8;
        int off = atomicAdd(&lhist[b], 1);
        stage[lbase[b] + off] = make_int2(ls[i], ld[i]);
    }
}

__global__ void place_k(const int2* __restrict__ stage, int* __restrict__ cursor,
                        int* __restrict__ csr_src, int E) {
    int e = blockIdx.x * blockDim.x + threadIdx.x;
    if (e < E) {
        int2 p = stage[e];
        int pos = atomicAdd(&cursor[p.y], 1);
        csr_src[pos] = p.x;
    }
}

__global__ void scatter_k(const int* __restrict__ src, const int* __restrict__ dst,
                          int* __restrict__ cursor, int* __restrict__ csr_src, int E) {
    int e = blockIdx.x * blockDim.x + threadIdx.x;
    if (e < E) {
        int pos = atomicAdd(&cursor[dst[e]], 1);
        csr_src[pos] = src[e];
    }
}

// ---------------- W -> MFMA B-fragment layout (bf16) ----------------
// For GEMM with K: frag f = ks*4 + ct (ks = k/32, ct = col/16).
// fw[f*512 + l*8 + i] = bf16( W[(ks*32 + (l>>4)*8 + i)*64 + ct*16 + (l&15)] )
__global__ void wfrag_k(const float* __restrict__ W1, const float* __restrict__ W2,
                        unsigned short* __restrict__ fw1, unsigned short* __restrict__ fw2) {
    int gid = blockIdx.x * blockDim.x + threadIdx.x;
    // W1: 16 frags (K=128), 8192 elems; W2: 8 frags (K=64), 4096 elems
    if (gid < 8192) {
        int f = gid >> 9, rem = gid & 511;
        int l = rem >> 3, i = rem & 7;
        int ks = f >> 2, ct = f & 3;
        int k = ks * 32 + ((l >> 4) << 3) + i;
        int c = ct * 16 + (l & 15);
        fw1[gid] = f2b(W1[k * 64 + c]);
    } else if (gid < 8192 + 4096) {
        int g = gid - 8192;
        int f = g >> 9, rem = g & 511;
        int l = rem >> 3, i = rem & 7;
        int ks = f >> 2, ct = f & 3;
        int k = ks * 32 + ((l >> 4) << 3) + i;
        int c = ct * 16 + (l & 15);
        fw2[g] = f2b(W2[k * 64 + c]);
    }
}

// ---------------- MFMA GEMM: Y[n x 64] = X[n x K] * W[K x 64] ----------------
// One wave per 16-row tile; B (all of W) in registers as frags.
// A layout: lane l -> m = l&15, k = (l>>4)*8 + i.  C/D: col = l&15,
// row = (l>>4)*4 + reg (m89-verified, dtype-independent).
template <int K, bool BF16IN>
__global__ __launch_bounds__(256) void mfma_gemm_k(
    const void* __restrict__ Xv, const unsigned short* __restrict__ FW,
    float* __restrict__ Y, int n) {
    constexpr int KS = K / 32;
    int wave   = (int)((blockIdx.x * blockDim.x + threadIdx.x) >> 6);
    int lane   = threadIdx.x & 63;
    int nwaves = (int)((gridDim.x * blockDim.x) >> 6);
    int ntiles = n >> 4;

    bf16x8 bfrag[KS][4];
    #pragma unroll
    for (int ks = 0; ks < KS; ++ks)
        #pragma unroll
        for (int ct = 0; ct < 4; ++ct)
            bfrag[ks][ct] = *reinterpret_cast<const bf16x8*>(FW + ((ks * 4 + ct) << 9) + (lane << 3));

    int rb = lane & 15;
    int kb = (lane >> 4) << 3;

    for (int tile = wave; tile < ntiles; tile += nwaves) {
        int row = (tile << 4) + rb;
        f32x4 acc[4];
        #pragma unroll
        for (int ct = 0; ct < 4; ++ct) acc[ct] = (f32x4){0.f, 0.f, 0.f, 0.f};

        #pragma unroll
        for (int ks = 0; ks < KS; ++ks) {
            bf16x8 af;
            if (BF16IN) {
                af = *reinterpret_cast<const bf16x8*>(
                    (const unsigned short*)Xv + (size_t)row * K + ks * 32 + kb);
            } else {
                const float* p = (const float*)Xv + (size_t)row * K + ks * 32 + kb;
                float4 u = *reinterpret_cast<const float4*>(p);
                float4 v = *reinterpret_cast<const float4*>(p + 4);
                af[0] = (short)f2b(u.x); af[1] = (short)f2b(u.y);
                af[2] = (short)f2b(u.z); af[3] = (short)f2b(u.w);
                af[4] = (short)f2b(v.x); af[5] = (short)f2b(v.y);
                af[6] = (short)f2b(v.z); af[7] = (short)f2b(v.w);
            }
            #pragma unroll
            for (int ct = 0; ct < 4; ++ct)
                acc[ct] = __builtin_amdgcn_mfma_f32_16x16x32_bf16(af, bfrag[ks][ct], acc[ct], 0, 0, 0);
        }

        int orow0 = (tile << 4) + ((lane >> 4) << 2);
        int ocol  = lane & 15;
        #pragma unroll
        for (int ct = 0; ct < 4; ++ct)
            #pragma unroll
            for (int r = 0; r < 4; ++r)
                Y[(size_t)(orow0 + r) * 64 + ct * 16 + ocol] = acc[ct][r];
    }

    // tail rows if n % 16 != 0 (dead for n = 100000)
    for (int r = (ntiles << 4) + wave; r < n; r += nwaves) {
        float a = 0.f;
        int ct = lane >> 4;        // unused name-shadow avoidance
        (void)ct;
        int c = lane;              // output column
        for (int k = 0; k < K; ++k) {
            float xv = BF16IN ? b2f(((const unsigned short*)Xv)[(size_t)r * K + k])
                              : ((const float*)Xv)[(size_t)r * K + k];
            int f  = (k >> 5) * 4 + (c >> 4);
            int lf = (c & 15) + (((k & 31) >> 3) << 4);
            int i  = k & 7;
            a = fmaf(xv, b2f(FW[(f << 9) + (lf << 3) + i]), a);
        }
        Y[(size_t)r * 64 + c] = a;
    }
}

// ---------------- CSR gather aggregation (one wave per node) ----------------
// MODE 0: h16 = bf16(relu(agg + b))              (layer 1, bf16 out for gemm2)
// MODE 1: out = sigmoid(dot(agg + b, Wl) + bl)   (layer 2 + head fused)
template <int MODE>
__global__ __launch_bounds__(256) void gather_k(
    const int* __restrict__ row_start, const int* __restrict__ csr_src,
    const float* __restrict__ dis, const float* __restrict__ t,
    const float* __restrict__ b, const float* __restrict__ Wl,
    const float* __restrict__ bl, void* __restrict__ outbuf, int n) {
    int node = (int)((blockIdx.x * blockDim.x + threadIdx.x) >> 6);
    int lane = threadIdx.x & 63;
    if (node >= n) return;
    int beg = row_start[node], end = row_start[node + 1];
    float dd = dis[node];
    float acc = dd * dd * t[(size_t)node * 64 + lane] + b[lane];

    int j = beg;
    for (; j + 3 < end; j += 4) {
        int s0 = csr_src[j], s1 = csr_src[j + 1], s2 = csr_src[j + 2], s3 = csr_src[j + 3];
        float w0 = dis[s0] * dd, w1 = dis[s1] * dd, w2 = dis[s2] * dd, w3 = dis[s3] * dd;
        acc = fmaf(w0, t[(size_t)s0 * 64 + lane], acc);
        acc = fmaf(w1, t[(size_t)s1 * 64 + lane], acc);
        acc = fmaf(w2, t[(size_t)s2 * 64 + lane], acc);
        acc = fmaf(w3, t[(size_t)s3 * 64 + lane], acc);
    }
    for (; j < end; ++j) {
        int s = csr_src[j];
        acc = fmaf(dis[s] * dd, t[(size_t)s * 64 + lane], acc);
    }

    if (MODE == 0) {
        ((unsigned short*)outbuf)[(size_t)node * 64 + lane] = f2b(fmaxf(acc, 0.f));
    } else {
        float v = acc * Wl[lane];
        #pragma unroll
        for (int m = 32; m >= 1; m >>= 1) v += __shfl_xor(v, m);
        if (lane == 0) ((float*)outbuf)[node] = 1.f / (1.f + expf(-(v + bl[0])));
    }
}

// ---------------- R1 fallback kernels (only if ws too small) ----------------

__global__ void relu_k(float* __restrict__ p, long long m) {
    long long i = (long long)blockIdx.x * blockDim.x + threadIdx.x;
    if (i < m) p[i] = fmaxf(p[i], 0.f);
}
__global__ void deg_init_k(float* __restrict__ deg, int n) {
    int i = blockIdx.x * blockDim.x + threadIdx.x;
    if (i < n) deg[i] = 1.0f;
}
__global__ void deg_edges_k(const int* __restrict__ dst, float* __restrict__ deg, int E) {
    int e = blockIdx.x * blockDim.x + threadIdx.x;
    if (e < E) atomicAdd(&deg[dst[e]], 1.0f);
}
__global__ void dis_k(float* __restrict__ deg, int n) {
    int i = blockIdx.x * blockDim.x + threadIdx.x;
    if (i < n) deg[i] = rsqrtf(deg[i]);
}
__global__ void init_agg_k(const float* __restrict__ t, const float* __restrict__ dis,
                           const float* __restrict__ b, float* __restrict__ agg, int n) {
    int idx = blockIdx.x * blockDim.x + threadIdx.x;
    if (idx >= n * 64) return;
    int i = idx >> 6, jj = idx & 63;
    float ds = dis[i];
    agg[idx] = ds * ds * t[idx] + b[jj];
}
__global__ __launch_bounds__(256) void agg_edges_k(
    const int* __restrict__ src, const int* __restrict__ dst,
    const float* __restrict__ dis, const float* __restrict__ t,
    float* __restrict__ agg, int E) {
    int e    = (int)((blockIdx.x * blockDim.x + threadIdx.x) >> 6);
    int lane = threadIdx.x & 63;
    if (e >= E) return;
    int s = src[e], d = dst[e];
    float w = dis[s] * dis[d];
    atomicAdd(&agg[(size_t)d * 64 + lane], w * t[(size_t)s * 64 + lane]);
}
__global__ __launch_bounds__(256) void final_k(
    const float* __restrict__ agg, const float* __restrict__ Wl,
    const float* __restrict__ bl, float* __restrict__ out, int n) {
    int node = (int)((blockIdx.x * blockDim.x + threadIdx.x) >> 6);
    int lane = threadIdx.x & 63;
    if (node >= n) return;
    float v = agg[(size_t)node * 64 + lane] * Wl[lane];
    #pragma unroll
    for (int m = 32; m >= 1; m >>= 1) v += __shfl_xor(v, m);
    if (lane == 0) out[node] = 1.f / (1.f + expf(-(v + bl[0])));
}

// legacy 4-row fp32 GEMM kept for the fallback path
template <int K>
__global__ __launch_bounds__(256) void gemm_rows4_k(
    const float* __restrict__ X, const float* __restrict__ W,
    float* __restrict__ Y, int n) {
    __shared__ float Ws[K * 64];
    for (int t = threadIdx.x; t < K * 64; t += blockDim.x) Ws[t] = W[t];
    __syncthreads();
    int wave   = (int)((blockIdx.x * blockDim.x + threadIdx.x) >> 6);
    int lane   = threadIdx.x & 63;
    int nwaves = (int)((gridDim.x * blockDim.x) >> 6);
    for (int r = wave; r < n; r += nwaves) {
        const float* xr = X + (size_t)r * K;
        float acc = 0.f;
        for (int k = 0; k < K; k += 4) {
            float4 a = *reinterpret_cast<const float4*>(xr + k);
            acc = fmaf(a.x, Ws[(k + 0) * 64 + lane], acc);
            acc = fmaf(a.y, Ws[(k + 1) * 64 + lane], acc);
            acc = fmaf(a.z, Ws[(k + 2) * 64 + lane], acc);
            acc = fmaf(a.w, Ws[(k + 3) * 64 + lane], acc);
        }
        Y[(size_t)r * 64 + lane] = acc;
    }
}

// ---------------------------------------------------------------------------

extern "C" void kernel_launch(void* const* d_in, const int* in_sizes, int n_in,
                              void* d_out, int out_size, void* d_ws, size_t ws_size,
                              hipStream_t stream) {
    const float* x  = (const float*)d_in[0];
    const int*   ei = (const int*)d_in[1];
    const float* W1 = (const float*)d_in[2];
    const float* b1 = (const float*)d_in[3];
    const float* W2 = (const float*)d_in[4];
    const float* b2 = (const float*)d_in[5];
    const float* Wl = (const float*)d_in[6];
    const float* bl = (const float*)d_in[7];
    float* out = (float*)d_out;

    const int n = in_sizes[0] / 128;      // 100000
    const int E = in_sizes[1] / 2;        // 1600000
    const int* src = ei;
    const int* dst = ei + E;

    const int B = 256;
    dim3 blk(B);
    auto align512 = [](size_t v) { return (v + 511) & ~(size_t)511; };

    // workspace layout
    char* ws = (char*)d_ws;
    size_t off = 0;
    float*          dis     = (float*)(ws + off); off = align512(off + (size_t)n * 4);
    int*            hist    = (int*)  (ws + off); off = align512(off + (size_t)n * 4);
    int*            row_st  = (int*)  (ws + off); off = align512(off + (size_t)(n + 1) * 4);
    int*            cursor  = (int*)  (ws + off); off = align512(off + (size_t)n * 4);
    int*            bcur    = (int*)  (ws + off); off = align512(off + (size_t)NBMAX * 4);
    int*            csr_src = (int*)  (ws + off); off = align512(off + (size_t)E * 4);
    float*          bufA    = (float*)(ws + off); off = align512(off + (size_t)n * 64 * 4);
    unsigned short* h16     = (unsigned short*)(ws + off); off = align512(off + (size_t)n * 64 * 2);
    unsigned short* fw1     = (unsigned short*)(ws + off); off = align512(off + 8192 * 2);
    unsigned short* fw2     = (unsigned short*)(ws + off); off = align512(off + 4096 * 2);
    size_t need_csr = off;

    if (ws_size >= need_csr && (n & 15) == 0) {
        const int nbuckets = (n + 255) >> 8;

        // ---- W fragment packing (tiny) ----
        wfrag_k<<<48, blk, 0, stream>>>(W1, W2, fw1, fw2);

        // ---- CSR build ----
        hipMemsetAsync(hist, 0, (size_t)n * 4, stream);
        hist_k<<<(E + B - 1) / B, blk, 0, stream>>>(dst, hist, E);
        dis_from_hist_k<<<(n + B - 1) / B, blk, 0, stream>>>(hist, dis, n);
        int nb = (n + SCAN_CHUNK - 1) / SCAN_CHUNK;
        int* bsum = csr_src + (size_t)E - nb - 1;   // scratch; consumed before csr writes
        scan_partial_k<<<nb, blk, 0, stream>>>(hist, bsum, n);
        scan_bsum_k<<<1, 64, 0, stream>>>(bsum, nb);
        scan_final_k<<<nb, blk, 0, stream>>>(hist, bsum, row_st, cursor, n);

        if (nbuckets <= NBMAX) {
            int2* stage = (int2*)bufA;   // bufA dead until gemm1
            bucket_init_k<<<(nbuckets + B - 1) / B, blk, 0, stream>>>(row_st, bcur, nbuckets);
            partition_k<<<(E + EPB - 1) / EPB, blk, 0, stream>>>(src, dst, bcur, stage, E, nbuckets);
            place_k<<<(E + B - 1) / B, blk, 0, stream>>>(stage, cursor, csr_src, E);
        } else {
            scatter_k<<<(E + B - 1) / B, blk, 0, stream>>>(src, dst, cursor, csr_src, E);
        }

        int gemm_blocks = ((n >> 4) + 3) / 4;   // one wave per 16-row tile

        // ---- layer 1: bufA = bf16mfma(x, W1) ; h16 = bf16(relu(agg + b1)) ----
        mfma_gemm_k<128, false><<<gemm_blocks, blk, 0, stream>>>(x, fw1, bufA, n);
        gather_k<0><<<((size_t)n * 64 + B - 1) / B, blk, 0, stream>>>(
            row_st, csr_src, dis, bufA, b1, Wl, bl, h16, n);

        // ---- layer 2 + head: bufA = bf16mfma(h16, W2) ; out = sigmoid(...) ----
        mfma_gemm_k<64, true><<<gemm_blocks, blk, 0, stream>>>(h16, fw2, bufA, n);
        gather_k<1><<<((size_t)n * 64 + B - 1) / B, blk, 0, stream>>>(
            row_st, csr_src, dis, bufA, b2, Wl, bl, out, n);
    } else {
        // ---- fallback: atomic scatter, fp32 GEMM ----
        size_t o2 = 0;
        float* dis2 = (float*)(ws + o2); o2 = align512(o2 + (size_t)n * 4);
        float* bA   = (float*)(ws + o2); o2 += (size_t)n * 64 * 4;
        float* bB   = (float*)(ws + o2);

        deg_init_k<<<(n + B - 1) / B, blk, 0, stream>>>(dis2, n);
        deg_edges_k<<<(E + B - 1) / B, blk, 0, stream>>>(dst, dis2, E);
        dis_k<<<(n + B - 1) / B, blk, 0, stream>>>(dis2, n);

        gemm_rows4_k<128><<<2048, blk, 0, stream>>>(x, W1, bA, n);
        init_agg_k<<<((size_t)n * 64 + B - 1) / B, blk, 0, stream>>>(bA, dis2, b1, bB, n);
        agg_edges_k<<<(E + 3) / 4, blk, 0, stream>>>(src, dst, dis2, bA, bB, E);
        relu_k<<<((size_t)n * 64 + B - 1) / B, blk, 0, stream>>>(bB, (long long)n * 64);

        gemm_rows4_k<64><<<2048, blk, 0, stream>>>(bB, W2, bA, n);
        init_agg_k<<<((size_t)n * 64 + B - 1) / B, blk, 0, stream>>>(bA, dis2, b2, bB, n);
        agg_edges_k<<<(E + 3) / 4, blk, 0, stream>>>(src, dst, dis2, bA, bB, E);

        final_k<<<(n + 3) / 4, blk, 0, stream>>>(bB, Wl, bl, out, n);
    }
}

// Round 6
// 311.238 us; speedup vs baseline: 3.1748x; 1.0520x over previous
//
#include <hip/hip_runtime.h>
#include <hip/hip_bf16.h>

// ---------------------------------------------------------------------------
// EnhancedGNN: 2-layer GCN + linear head + sigmoid.
// R6: bf16 feature buffers for gathers (halve gather bytes) and dis[src]
//     pre-scaling folded into GEMM stores (gather inner loop = pure row-sum).
//     MFMA GEMMs (16x16x32) + bucketed two-phase CSR scatter as before.
// ---------------------------------------------------------------------------

#define SCAN_CHUNK 1024
#define EPB 4096      // edges per partition block
#define NBMAX 512     // max buckets (n/256)

typedef __attribute__((ext_vector_type(8))) short bf16x8;
typedef __attribute__((ext_vector_type(4))) float f32x4;

__device__ __forceinline__ unsigned short f2b(float f) {   // fp32->bf16 RNE
    unsigned u = __builtin_bit_cast(unsigned, f);
    u += 0x7fffu + ((u >> 16) & 1u);
    return (unsigned short)(u >> 16);
}
__device__ __forceinline__ float b2f(unsigned short h) {
    unsigned u = (unsigned)h << 16;
    return __builtin_bit_cast(float, u);
}

// ---------------- CSR build ----------------

__global__ void hist_k(const int* __restrict__ dst, int* __restrict__ hist, int E) {
    int e = blockIdx.x * blockDim.x + threadIdx.x;
    if (e < E) atomicAdd(&hist[dst[e]], 1);
}

__global__ void dis_from_hist_k(const int* __restrict__ hist, float* __restrict__ dis, int n) {
    int i = blockIdx.x * blockDim.x + threadIdx.x;
    if (i < n) dis[i] = rsqrtf((float)hist[i] + 1.0f);
}

__global__ void scan_partial_k(const int* __restrict__ hist, int* __restrict__ bsum, int n) {
    __shared__ int sdata[256];
    int base = blockIdx.x * SCAN_CHUNK;
    int t = threadIdx.x;
    int s = 0;
    for (int i = t; i < SCAN_CHUNK; i += 256) {
        int idx = base + i;
        s += (idx < n) ? hist[idx] : 0;
    }
    sdata[t] = s; __syncthreads();
    for (int m = 128; m > 0; m >>= 1) {
        if (t < m) sdata[t] += sdata[t + m];
        __syncthreads();
    }
    if (t == 0) bsum[blockIdx.x] = sdata[0];
}

__global__ void scan_bsum_k(int* __restrict__ bsum, int nb) {
    if (threadIdx.x == 0 && blockIdx.x == 0) {
        int run = 0;
        for (int i = 0; i < nb; ++i) { int v = bsum[i]; bsum[i] = run; run += v; }
    }
}

__global__ void scan_final_k(const int* __restrict__ hist, const int* __restrict__ bsum,
                             int* __restrict__ row_start, int* __restrict__ cursor, int n) {
    __shared__ int tsum[256];
    int base = blockIdx.x * SCAN_CHUNK;
    int t = threadIdx.x;
    int idx0 = base + t * 4;
    int v[4]; int s = 0;
    #pragma unroll
    for (int k = 0; k < 4; ++k) { int idx = idx0 + k; v[k] = (idx < n) ? hist[idx] : 0; s += v[k]; }
    tsum[t] = s; __syncthreads();
    #pragma unroll
    for (int off = 1; off < 256; off <<= 1) {
        int val = (t >= off) ? tsum[t - off] : 0;
        __syncthreads();
        tsum[t] += val;
        __syncthreads();
    }
    int excl = (t > 0 ? tsum[t - 1] : 0) + bsum[blockIdx.x];
    #pragma unroll
    for (int k = 0; k < 4; ++k) {
        int idx = idx0 + k;
        if (idx < n) { row_start[idx] = excl; cursor[idx] = excl; }
        excl += v[k];
        if (idx == n - 1) row_start[n] = excl;   // total = E
    }
}

__global__ void bucket_init_k(const int* __restrict__ row_start, int* __restrict__ bucket_cur, int nbuckets) {
    int b = blockIdx.x * blockDim.x + threadIdx.x;
    if (b < nbuckets) bucket_cur[b] = row_start[b << 8];
}

__global__ __launch_bounds__(256) void partition_k(
    const int* __restrict__ src, const int* __restrict__ dst,
    int* __restrict__ bucket_cur, int2* __restrict__ stage, int E, int nbuckets) {
    __shared__ int ls[EPB];
    __shared__ int ld[EPB];
    __shared__ int lhist[NBMAX];
    __shared__ int lbase[NBMAX];
    int e0 = blockIdx.x * EPB;
    int cnt = min(EPB, E - e0);
    int t = threadIdx.x;
    for (int i = t; i < cnt; i += 256) { ls[i] = src[e0 + i]; ld[i] = dst[e0 + i]; }
    for (int b = t; b < nbuckets; b += 256) lhist[b] = 0;
    __syncthreads();
    for (int i = t; i < cnt; i += 256) atomicAdd(&lhist[ld[i] >> 8], 1);
    __syncthreads();
    for (int b = t; b < nbuckets; b += 256) {
        int c = lhist[b];
        lbase[b] = (c > 0) ? atomicAdd(&bucket_cur[b], c) : 0;
        lhist[b] = 0;
    }
    __syncthreads();
    for (int i = t; i < cnt; i += 256) {
        int b  = ld[i] >> 8;
        int off = atomicAdd(&lhist[b], 1);
        stage[lbase[b] + off] = make_int2(ls[i], ld[i]);
    }
}

__global__ void place_k(const int2* __restrict__ stage, int* __restrict__ cursor,
                        int* __restrict__ csr_src, int E) {
    int e = blockIdx.x * blockDim.x + threadIdx.x;
    if (e < E) {
        int2 p = stage[e];
        int pos = atomicAdd(&cursor[p.y], 1);
        csr_src[pos] = p.x;
    }
}

__global__ void scatter_k(const int* __restrict__ src, const int* __restrict__ dst,
                          int* __restrict__ cursor, int* __restrict__ csr_src, int E) {
    int e = blockIdx.x * blockDim.x + threadIdx.x;
    if (e < E) {
        int pos = atomicAdd(&cursor[dst[e]], 1);
        csr_src[pos] = src[e];
    }
}

// ---------------- W -> MFMA B-fragment layout (bf16) ----------------
__global__ void wfrag_k(const float* __restrict__ W1, const float* __restrict__ W2,
                        unsigned short* __restrict__ fw1, unsigned short* __restrict__ fw2) {
    int gid = blockIdx.x * blockDim.x + threadIdx.x;
    if (gid < 8192) {
        int f = gid >> 9, rem = gid & 511;
        int l = rem >> 3, i = rem & 7;
        int ks = f >> 2, ct = f & 3;
        int k = ks * 32 + ((l >> 4) << 3) + i;
        int c = ct * 16 + (l & 15);
        fw1[gid] = f2b(W1[k * 64 + c]);
    } else if (gid < 8192 + 4096) {
        int g = gid - 8192;
        int f = g >> 9, rem = g & 511;
        int l = rem >> 3, i = rem & 7;
        int ks = f >> 2, ct = f & 3;
        int k = ks * 32 + ((l >> 4) << 3) + i;
        int c = ct * 16 + (l & 15);
        fw2[g] = f2b(W2[k * 64 + c]);
    }
}

// ---------------- MFMA GEMM: Y[r,:] = bf16( dis[r] * (X[r,:] @ W) ) ----------
// One wave per 16-row tile; all of W in registers as B-frags.
// A: lane l -> (m = l&15, k = (l>>4)*8 + i). C/D: col = l&15, row = (l>>4)*4+reg.
template <int K, bool BF16IN>
__global__ __launch_bounds__(256) void mfma_gemm_k(
    const void* __restrict__ Xv, const unsigned short* __restrict__ FW,
    const float* __restrict__ dis, unsigned short* __restrict__ Y, int n) {
    constexpr int KS = K / 32;
    int wave   = (int)((blockIdx.x * blockDim.x + threadIdx.x) >> 6);
    int lane   = threadIdx.x & 63;
    int nwaves = (int)((gridDim.x * blockDim.x) >> 6);
    int ntiles = n >> 4;

    bf16x8 bfrag[KS][4];
    #pragma unroll
    for (int ks = 0; ks < KS; ++ks)
        #pragma unroll
        for (int ct = 0; ct < 4; ++ct)
            bfrag[ks][ct] = *reinterpret_cast<const bf16x8*>(FW + ((ks * 4 + ct) << 9) + (lane << 3));

    int rb = lane & 15;
    int kb = (lane >> 4) << 3;

    for (int tile = wave; tile < ntiles; tile += nwaves) {
        int row = (tile << 4) + rb;
        f32x4 acc[4];
        #pragma unroll
        for (int ct = 0; ct < 4; ++ct) acc[ct] = (f32x4){0.f, 0.f, 0.f, 0.f};

        #pragma unroll
        for (int ks = 0; ks < KS; ++ks) {
            bf16x8 af;
            if (BF16IN) {
                af = *reinterpret_cast<const bf16x8*>(
                    (const unsigned short*)Xv + (size_t)row * K + ks * 32 + kb);
            } else {
                const float* p = (const float*)Xv + (size_t)row * K + ks * 32 + kb;
                float4 u = *reinterpret_cast<const float4*>(p);
                float4 v = *reinterpret_cast<const float4*>(p + 4);
                af[0] = (short)f2b(u.x); af[1] = (short)f2b(u.y);
                af[2] = (short)f2b(u.z); af[3] = (short)f2b(u.w);
                af[4] = (short)f2b(v.x); af[5] = (short)f2b(v.y);
                af[6] = (short)f2b(v.z); af[7] = (short)f2b(v.w);
            }
            #pragma unroll
            for (int ct = 0; ct < 4; ++ct)
                acc[ct] = __builtin_amdgcn_mfma_f32_16x16x32_bf16(af, bfrag[ks][ct], acc[ct], 0, 0, 0);
        }

        int orow0 = (tile << 4) + ((lane >> 4) << 2);
        int ocol  = lane & 15;
        float dv0 = dis[orow0], dv1 = dis[orow0 + 1], dv2 = dis[orow0 + 2], dv3 = dis[orow0 + 3];
        #pragma unroll
        for (int ct = 0; ct < 4; ++ct) {
            Y[(size_t)(orow0 + 0) * 64 + ct * 16 + ocol] = f2b(acc[ct][0] * dv0);
            Y[(size_t)(orow0 + 1) * 64 + ct * 16 + ocol] = f2b(acc[ct][1] * dv1);
            Y[(size_t)(orow0 + 2) * 64 + ct * 16 + ocol] = f2b(acc[ct][2] * dv2);
            Y[(size_t)(orow0 + 3) * 64 + ct * 16 + ocol] = f2b(acc[ct][3] * dv3);
        }
    }

    // tail rows if n % 16 != 0 (dead for n = 100000)
    for (int r = (ntiles << 4) + wave; r < n; r += nwaves) {
        float a = 0.f;
        int c = lane;
        for (int k = 0; k < K; ++k) {
            float xv = BF16IN ? b2f(((const unsigned short*)Xv)[(size_t)r * K + k])
                              : ((const float*)Xv)[(size_t)r * K + k];
            int f  = (k >> 5) * 4 + (c >> 4);
            int lf = (c & 15) + (((k & 31) >> 3) << 4);
            int i  = k & 7;
            a = fmaf(xv, b2f(FW[(f << 9) + (lf << 3) + i]), a);
        }
        Y[(size_t)r * 64 + c] = f2b(a * dis[r]);
    }
}

// ---------------- CSR gather aggregation (one wave per node) ----------------
// tp holds dis[r]-pre-scaled rows in bf16. agg_row = dd * (tp[node] + sum tp[s]).
// MODE 0: h16 = bf16(relu(agg + b))              (layer 1, bf16 out for gemm2)
// MODE 1: out = sigmoid(dot(agg + b, Wl) + bl)   (layer 2 + head fused)
template <int MODE>
__global__ __launch_bounds__(256) void gather_k(
    const int* __restrict__ row_start, const int* __restrict__ csr_src,
    const float* __restrict__ dis, const unsigned short* __restrict__ tp,
    const float* __restrict__ b, const float* __restrict__ Wl,
    const float* __restrict__ bl, void* __restrict__ outbuf, int n) {
    int node = (int)((blockIdx.x * blockDim.x + threadIdx.x) >> 6);
    int lane = threadIdx.x & 63;
    if (node >= n) return;
    int beg = row_start[node], end = row_start[node + 1];
    float dd = dis[node];
    float acc = b2f(tp[(size_t)node * 64 + lane]);   // self term (pre-scaled by dd)

    int j = beg;
    for (; j + 3 < end; j += 4) {
        int s0 = csr_src[j], s1 = csr_src[j + 1], s2 = csr_src[j + 2], s3 = csr_src[j + 3];
        acc += b2f(tp[(size_t)s0 * 64 + lane]);
        acc += b2f(tp[(size_t)s1 * 64 + lane]);
        acc += b2f(tp[(size_t)s2 * 64 + lane]);
        acc += b2f(tp[(size_t)s3 * 64 + lane]);
    }
    for (; j < end; ++j)
        acc += b2f(tp[(size_t)csr_src[j] * 64 + lane]);

    float r = fmaf(dd, acc, b[lane]);

    if (MODE == 0) {
        ((unsigned short*)outbuf)[(size_t)node * 64 + lane] = f2b(fmaxf(r, 0.f));
    } else {
        float v = r * Wl[lane];
        #pragma unroll
        for (int m = 32; m >= 1; m >>= 1) v += __shfl_xor(v, m);
        if (lane == 0) ((float*)outbuf)[node] = 1.f / (1.f + expf(-(v + bl[0])));
    }
}

// ---------------- fallback kernels (only if ws too small / n%16) ----------------

__global__ void relu_k(float* __restrict__ p, long long m) {
    long long i = (long long)blockIdx.x * blockDim.x + threadIdx.x;
    if (i < m) p[i] = fmaxf(p[i], 0.f);
}
__global__ void deg_init_k(float* __restrict__ deg, int n) {
    int i = blockIdx.x * blockDim.x + threadIdx.x;
    if (i < n) deg[i] = 1.0f;
}
__global__ void deg_edges_k(const int* __restrict__ dst, float* __restrict__ deg, int E) {
    int e = blockIdx.x * blockDim.x + threadIdx.x;
    if (e < E) atomicAdd(&deg[dst[e]], 1.0f);
}
__global__ void dis_k(float* __restrict__ deg, int n) {
    int i = blockIdx.x * blockDim.x + threadIdx.x;
    if (i < n) deg[i] = rsqrtf(deg[i]);
}
__global__ void init_agg_k(const float* __restrict__ t, const float* __restrict__ dis,
                           const float* __restrict__ b, float* __restrict__ agg, int n) {
    int idx = blockIdx.x * blockDim.x + threadIdx.x;
    if (idx >= n * 64) return;
    int i = idx >> 6, jj = idx & 63;
    float ds = dis[i];
    agg[idx] = ds * ds * t[idx] + b[jj];
}
__global__ __launch_bounds__(256) void agg_edges_k(
    const int* __restrict__ src, const int* __restrict__ dst,
    const float* __restrict__ dis, const float* __restrict__ t,
    float* __restrict__ agg, int E) {
    int e    = (int)((blockIdx.x * blockDim.x + threadIdx.x) >> 6);
    int lane = threadIdx.x & 63;
    if (e >= E) return;
    int s = src[e], d = dst[e];
    float w = dis[s] * dis[d];
    atomicAdd(&agg[(size_t)d * 64 + lane], w * t[(size_t)s * 64 + lane]);
}
__global__ __launch_bounds__(256) void final_k(
    const float* __restrict__ agg, const float* __restrict__ Wl,
    const float* __restrict__ bl, float* __restrict__ out, int n) {
    int node = (int)((blockIdx.x * blockDim.x + threadIdx.x) >> 6);
    int lane = threadIdx.x & 63;
    if (node >= n) return;
    float v = agg[(size_t)node * 64 + lane] * Wl[lane];
    #pragma unroll
    for (int m = 32; m >= 1; m >>= 1) v += __shfl_xor(v, m);
    if (lane == 0) out[node] = 1.f / (1.f + expf(-(v + bl[0])));
}
template <int K>
__global__ __launch_bounds__(256) void gemm_rows4_k(
    const float* __restrict__ X, const float* __restrict__ W,
    float* __restrict__ Y, int n) {
    __shared__ float Ws[K * 64];
    for (int t = threadIdx.x; t < K * 64; t += blockDim.x) Ws[t] = W[t];
    __syncthreads();
    int wave   = (int)((blockIdx.x * blockDim.x + threadIdx.x) >> 6);
    int lane   = threadIdx.x & 63;
    int nwaves = (int)((gridDim.x * blockDim.x) >> 6);
    for (int r = wave; r < n; r += nwaves) {
        const float* xr = X + (size_t)r * K;
        float acc = 0.f;
        for (int k = 0; k < K; k += 4) {
            float4 a = *reinterpret_cast<const float4*>(xr + k);
            acc = fmaf(a.x, Ws[(k + 0) * 64 + lane], acc);
            acc = fmaf(a.y, Ws[(k + 1) * 64 + lane], acc);
            acc = fmaf(a.z, Ws[(k + 2) * 64 + lane], acc);
            acc = fmaf(a.w, Ws[(k + 3) * 64 + lane], acc);
        }
        Y[(size_t)r * 64 + lane] = acc;
    }
}

// ---------------------------------------------------------------------------

extern "C" void kernel_launch(void* const* d_in, const int* in_sizes, int n_in,
                              void* d_out, int out_size, void* d_ws, size_t ws_size,
                              hipStream_t stream) {
    const float* x  = (const float*)d_in[0];
    const int*   ei = (const int*)d_in[1];
    const float* W1 = (const float*)d_in[2];
    const float* b1 = (const float*)d_in[3];
    const float* W2 = (const float*)d_in[4];
    const float* b2 = (const float*)d_in[5];
    const float* Wl = (const float*)d_in[6];
    const float* bl = (const float*)d_in[7];
    float* out = (float*)d_out;

    const int n = in_sizes[0] / 128;      // 100000
    const int E = in_sizes[1] / 2;        // 1600000
    const int* src = ei;
    const int* dst = ei + E;

    const int B = 256;
    dim3 blk(B);
    auto align512 = [](size_t v) { return (v + 511) & ~(size_t)511; };

    // workspace layout (~46.5 MB)
    char* ws = (char*)d_ws;
    size_t off = 0;
    float*          dis     = (float*)(ws + off); off = align512(off + (size_t)n * 4);
    int*            hist    = (int*)  (ws + off); off = align512(off + (size_t)n * 4);
    int*            row_st  = (int*)  (ws + off); off = align512(off + (size_t)(n + 1) * 4);
    int*            cursor  = (int*)  (ws + off); off = align512(off + (size_t)n * 4);
    int*            bcur    = (int*)  (ws + off); off = align512(off + (size_t)NBMAX * 4);
    int*            csr_src = (int*)  (ws + off); off = align512(off + (size_t)E * 4);
    unsigned short* bufA16  = (unsigned short*)(ws + off); off = align512(off + (size_t)n * 64 * 2);
    unsigned short* h16     = (unsigned short*)(ws + off); off = align512(off + (size_t)n * 64 * 2);
    int2*           stage   = (int2*) (ws + off); off = align512(off + (size_t)E * 8);
    unsigned short* fw1     = (unsigned short*)(ws + off); off = align512(off + 8192 * 2);
    unsigned short* fw2     = (unsigned short*)(ws + off); off = align512(off + 4096 * 2);
    size_t need_csr = off;

    if (ws_size >= need_csr && (n & 15) == 0) {
        const int nbuckets = (n + 255) >> 8;

        // ---- W fragment packing (tiny) ----
        wfrag_k<<<48, blk, 0, stream>>>(W1, W2, fw1, fw2);

        // ---- CSR build ----
        hipMemsetAsync(hist, 0, (size_t)n * 4, stream);
        hist_k<<<(E + B - 1) / B, blk, 0, stream>>>(dst, hist, E);
        dis_from_hist_k<<<(n + B - 1) / B, blk, 0, stream>>>(hist, dis, n);
        int nb = (n + SCAN_CHUNK - 1) / SCAN_CHUNK;
        int* bsum = csr_src + (size_t)E - nb - 1;   // scratch; consumed before csr writes
        scan_partial_k<<<nb, blk, 0, stream>>>(hist, bsum, n);
        scan_bsum_k<<<1, 64, 0, stream>>>(bsum, nb);
        scan_final_k<<<nb, blk, 0, stream>>>(hist, bsum, row_st, cursor, n);

        if (nbuckets <= NBMAX) {
            bucket_init_k<<<(nbuckets + B - 1) / B, blk, 0, stream>>>(row_st, bcur, nbuckets);
            partition_k<<<(E + EPB - 1) / EPB, blk, 0, stream>>>(src, dst, bcur, stage, E, nbuckets);
            place_k<<<(E + B - 1) / B, blk, 0, stream>>>(stage, cursor, csr_src, E);
        } else {
            scatter_k<<<(E + B - 1) / B, blk, 0, stream>>>(src, dst, cursor, csr_src, E);
        }

        int gemm_blocks = ((n >> 4) + 3) / 4;   // one wave per 16-row tile

        // ---- layer 1: bufA16 = bf16(dis * (x@W1)) ; h16 = bf16(relu(agg+b1)) ----
        mfma_gemm_k<128, false><<<gemm_blocks, blk, 0, stream>>>(x, fw1, dis, bufA16, n);
        gather_k<0><<<((size_t)n * 64 + B - 1) / B, blk, 0, stream>>>(
            row_st, csr_src, dis, bufA16, b1, Wl, bl, h16, n);

        // ---- layer 2 + head: bufA16 = bf16(dis * (h16@W2)) ; out = sigmoid ----
        mfma_gemm_k<64, true><<<gemm_blocks, blk, 0, stream>>>(h16, fw2, dis, bufA16, n);
        gather_k<1><<<((size_t)n * 64 + B - 1) / B, blk, 0, stream>>>(
            row_st, csr_src, dis, bufA16, b2, Wl, bl, out, n);
    } else {
        // ---- fallback: atomic scatter, fp32 GEMM ----
        size_t o2 = 0;
        float* dis2 = (float*)(ws + o2); o2 = align512(o2 + (size_t)n * 4);
        float* bA   = (float*)(ws + o2); o2 += (size_t)n * 64 * 4;
        float* bB   = (float*)(ws + o2);

        deg_init_k<<<(n + B - 1) / B, blk, 0, stream>>>(dis2, n);
        deg_edges_k<<<(E + B - 1) / B, blk, 0, stream>>>(dst, dis2, E);
        dis_k<<<(n + B - 1) / B, blk, 0, stream>>>(dis2, n);

        gemm_rows4_k<128><<<2048, blk, 0, stream>>>(x, W1, bA, n);
        init_agg_k<<<((size_t)n * 64 + B - 1) / B, blk, 0, stream>>>(bA, dis2, b1, bB, n);
        agg_edges_k<<<(E + 3) / 4, blk, 0, stream>>>(src, dst, dis2, bA, bB, E);
        relu_k<<<((size_t)n * 64 + B - 1) / B, blk, 0, stream>>>(bB, (long long)n * 64);

        gemm_rows4_k<64><<<2048, blk, 0, stream>>>(bB, W2, bA, n);
        init_agg_k<<<((size_t)n * 64 + B - 1) / B, blk, 0, stream>>>(bA, dis2, b2, bB, n);
        agg_edges_k<<<(E + 3) / 4, blk, 0, stream>>>(src, dst, dis2, bA, bB, E);

        final_k<<<(n + 3) / 4, blk, 0, stream>>>(bB, Wl, bl, out, n);
    }
}

// Round 7
// 274.952 us; speedup vs baseline: 3.5938x; 1.1320x over previous
//
#include <hip/hip_runtime.h>
#include <hip/hip_bf16.h>

// ---------------------------------------------------------------------------
// EnhancedGNN: 2-layer GCN + linear head + sigmoid.
// R7: latency-optimized gather — adjacency window vector-loaded once per wave
//     (indices broadcast via __shfl, removing the index-load from the critical
//     path) + 8 independent accumulators (8 row-loads in flight per wave).
//     Rest (MFMA GEMMs, bf16 pre-scaled features, bucketed CSR build) as R6.
// ---------------------------------------------------------------------------

#define SCAN_CHUNK 1024
#define EPB 4096      // edges per partition block
#define NBMAX 512     // max buckets (n/256)

typedef __attribute__((ext_vector_type(8))) short bf16x8;
typedef __attribute__((ext_vector_type(4))) float f32x4;

__device__ __forceinline__ unsigned short f2b(float f) {   // fp32->bf16 RNE
    unsigned u = __builtin_bit_cast(unsigned, f);
    u += 0x7fffu + ((u >> 16) & 1u);
    return (unsigned short)(u >> 16);
}
__device__ __forceinline__ float b2f(unsigned short h) {
    unsigned u = (unsigned)h << 16;
    return __builtin_bit_cast(float, u);
}

// ---------------- CSR build ----------------

__global__ void hist_k(const int* __restrict__ dst, int* __restrict__ hist, int E) {
    int e = blockIdx.x * blockDim.x + threadIdx.x;
    if (e < E) atomicAdd(&hist[dst[e]], 1);
}

__global__ void dis_from_hist_k(const int* __restrict__ hist, float* __restrict__ dis, int n) {
    int i = blockIdx.x * blockDim.x + threadIdx.x;
    if (i < n) dis[i] = rsqrtf((float)hist[i] + 1.0f);
}

__global__ void scan_partial_k(const int* __restrict__ hist, int* __restrict__ bsum, int n) {
    __shared__ int sdata[256];
    int base = blockIdx.x * SCAN_CHUNK;
    int t = threadIdx.x;
    int s = 0;
    for (int i = t; i < SCAN_CHUNK; i += 256) {
        int idx = base + i;
        s += (idx < n) ? hist[idx] : 0;
    }
    sdata[t] = s; __syncthreads();
    for (int m = 128; m > 0; m >>= 1) {
        if (t < m) sdata[t] += sdata[t + m];
        __syncthreads();
    }
    if (t == 0) bsum[blockIdx.x] = sdata[0];
}

__global__ void scan_bsum_k(int* __restrict__ bsum, int nb) {
    if (threadIdx.x == 0 && blockIdx.x == 0) {
        int run = 0;
        for (int i = 0; i < nb; ++i) { int v = bsum[i]; bsum[i] = run; run += v; }
    }
}

__global__ void scan_final_k(const int* __restrict__ hist, const int* __restrict__ bsum,
                             int* __restrict__ row_start, int* __restrict__ cursor, int n) {
    __shared__ int tsum[256];
    int base = blockIdx.x * SCAN_CHUNK;
    int t = threadIdx.x;
    int idx0 = base + t * 4;
    int v[4]; int s = 0;
    #pragma unroll
    for (int k = 0; k < 4; ++k) { int idx = idx0 + k; v[k] = (idx < n) ? hist[idx] : 0; s += v[k]; }
    tsum[t] = s; __syncthreads();
    #pragma unroll
    for (int off = 1; off < 256; off <<= 1) {
        int val = (t >= off) ? tsum[t - off] : 0;
        __syncthreads();
        tsum[t] += val;
        __syncthreads();
    }
    int excl = (t > 0 ? tsum[t - 1] : 0) + bsum[blockIdx.x];
    #pragma unroll
    for (int k = 0; k < 4; ++k) {
        int idx = idx0 + k;
        if (idx < n) { row_start[idx] = excl; cursor[idx] = excl; }
        excl += v[k];
        if (idx == n - 1) row_start[n] = excl;   // total = E
    }
}

__global__ void bucket_init_k(const int* __restrict__ row_start, int* __restrict__ bucket_cur, int nbuckets) {
    int b = blockIdx.x * blockDim.x + threadIdx.x;
    if (b < nbuckets) bucket_cur[b] = row_start[b << 8];
}

__global__ __launch_bounds__(256) void partition_k(
    const int* __restrict__ src, const int* __restrict__ dst,
    int* __restrict__ bucket_cur, int2* __restrict__ stage, int E, int nbuckets) {
    __shared__ int ls[EPB];
    __shared__ int ld[EPB];
    __shared__ int lhist[NBMAX];
    __shared__ int lbase[NBMAX];
    int e0 = blockIdx.x * EPB;
    int cnt = min(EPB, E - e0);
    int t = threadIdx.x;
    for (int i = t; i < cnt; i += 256) { ls[i] = src[e0 + i]; ld[i] = dst[e0 + i]; }
    for (int b = t; b < nbuckets; b += 256) lhist[b] = 0;
    __syncthreads();
    for (int i = t; i < cnt; i += 256) atomicAdd(&lhist[ld[i] >> 8], 1);
    __syncthreads();
    for (int b = t; b < nbuckets; b += 256) {
        int c = lhist[b];
        lbase[b] = (c > 0) ? atomicAdd(&bucket_cur[b], c) : 0;
        lhist[b] = 0;
    }
    __syncthreads();
    for (int i = t; i < cnt; i += 256) {
        int b  = ld[i] >> 8;
        int off = atomicAdd(&lhist[b], 1);
        stage[lbase[b] + off] = make_int2(ls[i], ld[i]);
    }
}

__global__ void place_k(const int2* __restrict__ stage, int* __restrict__ cursor,
                        int* __restrict__ csr_src, int E) {
    int e = blockIdx.x * blockDim.x + threadIdx.x;
    if (e < E) {
        int2 p = stage[e];
        int pos = atomicAdd(&cursor[p.y], 1);
        csr_src[pos] = p.x;
    }
}

__global__ void scatter_k(const int* __restrict__ src, const int* __restrict__ dst,
                          int* __restrict__ cursor, int* __restrict__ csr_src, int E) {
    int e = blockIdx.x * blockDim.x + threadIdx.x;
    if (e < E) {
        int pos = atomicAdd(&cursor[dst[e]], 1);
        csr_src[pos] = src[e];
    }
}

// ---------------- W -> MFMA B-fragment layout (bf16) ----------------
__global__ void wfrag_k(const float* __restrict__ W1, const float* __restrict__ W2,
                        unsigned short* __restrict__ fw1, unsigned short* __restrict__ fw2) {
    int gid = blockIdx.x * blockDim.x + threadIdx.x;
    if (gid < 8192) {
        int f = gid >> 9, rem = gid & 511;
        int l = rem >> 3, i = rem & 7;
        int ks = f >> 2, ct = f & 3;
        int k = ks * 32 + ((l >> 4) << 3) + i;
        int c = ct * 16 + (l & 15);
        fw1[gid] = f2b(W1[k * 64 + c]);
    } else if (gid < 8192 + 4096) {
        int g = gid - 8192;
        int f = g >> 9, rem = g & 511;
        int l = rem >> 3, i = rem & 7;
        int ks = f >> 2, ct = f & 3;
        int k = ks * 32 + ((l >> 4) << 3) + i;
        int c = ct * 16 + (l & 15);
        fw2[g] = f2b(W2[k * 64 + c]);
    }
}

// ---------------- MFMA GEMM: Y[r,:] = bf16( dis[r] * (X[r,:] @ W) ) ----------
template <int K, bool BF16IN>
__global__ __launch_bounds__(256) void mfma_gemm_k(
    const void* __restrict__ Xv, const unsigned short* __restrict__ FW,
    const float* __restrict__ dis, unsigned short* __restrict__ Y, int n) {
    constexpr int KS = K / 32;
    int wave   = (int)((blockIdx.x * blockDim.x + threadIdx.x) >> 6);
    int lane   = threadIdx.x & 63;
    int nwaves = (int)((gridDim.x * blockDim.x) >> 6);
    int ntiles = n >> 4;

    bf16x8 bfrag[KS][4];
    #pragma unroll
    for (int ks = 0; ks < KS; ++ks)
        #pragma unroll
        for (int ct = 0; ct < 4; ++ct)
            bfrag[ks][ct] = *reinterpret_cast<const bf16x8*>(FW + ((ks * 4 + ct) << 9) + (lane << 3));

    int rb = lane & 15;
    int kb = (lane >> 4) << 3;

    for (int tile = wave; tile < ntiles; tile += nwaves) {
        int row = (tile << 4) + rb;
        f32x4 acc[4];
        #pragma unroll
        for (int ct = 0; ct < 4; ++ct) acc[ct] = (f32x4){0.f, 0.f, 0.f, 0.f};

        #pragma unroll
        for (int ks = 0; ks < KS; ++ks) {
            bf16x8 af;
            if (BF16IN) {
                af = *reinterpret_cast<const bf16x8*>(
                    (const unsigned short*)Xv + (size_t)row * K + ks * 32 + kb);
            } else {
                const float* p = (const float*)Xv + (size_t)row * K + ks * 32 + kb;
                float4 u = *reinterpret_cast<const float4*>(p);
                float4 v = *reinterpret_cast<const float4*>(p + 4);
                af[0] = (short)f2b(u.x); af[1] = (short)f2b(u.y);
                af[2] = (short)f2b(u.z); af[3] = (short)f2b(u.w);
                af[4] = (short)f2b(v.x); af[5] = (short)f2b(v.y);
                af[6] = (short)f2b(v.z); af[7] = (short)f2b(v.w);
            }
            #pragma unroll
            for (int ct = 0; ct < 4; ++ct)
                acc[ct] = __builtin_amdgcn_mfma_f32_16x16x32_bf16(af, bfrag[ks][ct], acc[ct], 0, 0, 0);
        }

        int orow0 = (tile << 4) + ((lane >> 4) << 2);
        int ocol  = lane & 15;
        float dv0 = dis[orow0], dv1 = dis[orow0 + 1], dv2 = dis[orow0 + 2], dv3 = dis[orow0 + 3];
        #pragma unroll
        for (int ct = 0; ct < 4; ++ct) {
            Y[(size_t)(orow0 + 0) * 64 + ct * 16 + ocol] = f2b(acc[ct][0] * dv0);
            Y[(size_t)(orow0 + 1) * 64 + ct * 16 + ocol] = f2b(acc[ct][1] * dv1);
            Y[(size_t)(orow0 + 2) * 64 + ct * 16 + ocol] = f2b(acc[ct][2] * dv2);
            Y[(size_t)(orow0 + 3) * 64 + ct * 16 + ocol] = f2b(acc[ct][3] * dv3);
        }
    }

    for (int r = (ntiles << 4) + wave; r < n; r += nwaves) {
        float a = 0.f;
        int c = lane;
        for (int k = 0; k < K; ++k) {
            float xv = BF16IN ? b2f(((const unsigned short*)Xv)[(size_t)r * K + k])
                              : ((const float*)Xv)[(size_t)r * K + k];
            int f  = (k >> 5) * 4 + (c >> 4);
            int lf = (c & 15) + (((k & 31) >> 3) << 4);
            int i  = k & 7;
            a = fmaf(xv, b2f(FW[(f << 9) + (lf << 3) + i]), a);
        }
        Y[(size_t)r * 64 + c] = f2b(a * dis[r]);
    }
}

// ---------------- CSR gather aggregation (one wave per node) ----------------
// Adjacency window loaded once per 64 edges (lane-parallel), indices broadcast
// via __shfl; 8 independent accumulators keep 8 row-loads in flight.
// MODE 0: h16 = bf16(relu(dd*acc + b))          (layer 1, bf16 out for gemm2)
// MODE 1: out = sigmoid(dot(dd*acc + b, Wl)+bl) (layer 2 + head fused)
template <int MODE>
__global__ __launch_bounds__(256) void gather_k(
    const int* __restrict__ row_start, const int* __restrict__ csr_src,
    const float* __restrict__ dis, const unsigned short* __restrict__ tp,
    const float* __restrict__ b, const float* __restrict__ Wl,
    const float* __restrict__ bl, void* __restrict__ outbuf, int n) {
    int node = (int)((blockIdx.x * blockDim.x + threadIdx.x) >> 6);
    int lane = threadIdx.x & 63;
    if (node >= n) return;
    int beg = row_start[node], end = row_start[node + 1];
    float dd = dis[node];
    float a0 = b2f(tp[(size_t)node * 64 + lane]);   // self term (pre-scaled)
    float a1 = 0.f, a2 = 0.f, a3 = 0.f, a4 = 0.f, a5 = 0.f, a6 = 0.f, a7 = 0.f;

    for (int base = beg; base < end; base += 64) {
        int rem = end - base;
        int cnt = rem < 64 ? rem : 64;
        int idx = (lane < cnt) ? csr_src[base + lane] : 0;   // one coalesced load / 64 edges
        int j = 0;
        for (; j + 8 <= cnt; j += 8) {
            int s0 = __shfl(idx, j + 0), s1 = __shfl(idx, j + 1);
            int s2 = __shfl(idx, j + 2), s3 = __shfl(idx, j + 3);
            int s4 = __shfl(idx, j + 4), s5 = __shfl(idx, j + 5);
            int s6 = __shfl(idx, j + 6), s7 = __shfl(idx, j + 7);
            a0 += b2f(tp[(size_t)s0 * 64 + lane]);
            a1 += b2f(tp[(size_t)s1 * 64 + lane]);
            a2 += b2f(tp[(size_t)s2 * 64 + lane]);
            a3 += b2f(tp[(size_t)s3 * 64 + lane]);
            a4 += b2f(tp[(size_t)s4 * 64 + lane]);
            a5 += b2f(tp[(size_t)s5 * 64 + lane]);
            a6 += b2f(tp[(size_t)s6 * 64 + lane]);
            a7 += b2f(tp[(size_t)s7 * 64 + lane]);
        }
        if (j + 4 <= cnt) {
            int s0 = __shfl(idx, j + 0), s1 = __shfl(idx, j + 1);
            int s2 = __shfl(idx, j + 2), s3 = __shfl(idx, j + 3);
            a0 += b2f(tp[(size_t)s0 * 64 + lane]);
            a1 += b2f(tp[(size_t)s1 * 64 + lane]);
            a2 += b2f(tp[(size_t)s2 * 64 + lane]);
            a3 += b2f(tp[(size_t)s3 * 64 + lane]);
            j += 4;
        }
        for (; j < cnt; ++j) {
            int s = __shfl(idx, j);
            a4 += b2f(tp[(size_t)s * 64 + lane]);
        }
    }

    float acc = ((a0 + a1) + (a2 + a3)) + ((a4 + a5) + (a6 + a7));
    float r = fmaf(dd, acc, b[lane]);

    if (MODE == 0) {
        ((unsigned short*)outbuf)[(size_t)node * 64 + lane] = f2b(fmaxf(r, 0.f));
    } else {
        float v = r * Wl[lane];
        #pragma unroll
        for (int m = 32; m >= 1; m >>= 1) v += __shfl_xor(v, m);
        if (lane == 0) ((float*)outbuf)[node] = 1.f / (1.f + expf(-(v + bl[0])));
    }
}

// ---------------- fallback kernels (only if ws too small / n%16) ----------------

__global__ void relu_k(float* __restrict__ p, long long m) {
    long long i = (long long)blockIdx.x * blockDim.x + threadIdx.x;
    if (i < m) p[i] = fmaxf(p[i], 0.f);
}
__global__ void deg_init_k(float* __restrict__ deg, int n) {
    int i = blockIdx.x * blockDim.x + threadIdx.x;
    if (i < n) deg[i] = 1.0f;
}
__global__ void deg_edges_k(const int* __restrict__ dst, float* __restrict__ deg, int E) {
    int e = blockIdx.x * blockDim.x + threadIdx.x;
    if (e < E) atomicAdd(&deg[dst[e]], 1.0f);
}
__global__ void dis_k(float* __restrict__ deg, int n) {
    int i = blockIdx.x * blockDim.x + threadIdx.x;
    if (i < n) deg[i] = rsqrtf(deg[i]);
}
__global__ void init_agg_k(const float* __restrict__ t, const float* __restrict__ dis,
                           const float* __restrict__ b, float* __restrict__ agg, int n) {
    int idx = blockIdx.x * blockDim.x + threadIdx.x;
    if (idx >= n * 64) return;
    int i = idx >> 6, jj = idx & 63;
    float ds = dis[i];
    agg[idx] = ds * ds * t[idx] + b[jj];
}
__global__ __launch_bounds__(256) void agg_edges_k(
    const int* __restrict__ src, const int* __restrict__ dst,
    const float* __restrict__ dis, const float* __restrict__ t,
    float* __restrict__ agg, int E) {
    int e    = (int)((blockIdx.x * blockDim.x + threadIdx.x) >> 6);
    int lane = threadIdx.x & 63;
    if (e >= E) return;
    int s = src[e], d = dst[e];
    float w = dis[s] * dis[d];
    atomicAdd(&agg[(size_t)d * 64 + lane], w * t[(size_t)s * 64 + lane]);
}
__global__ __launch_bounds__(256) void final_k(
    const float* __restrict__ agg, const float* __restrict__ Wl,
    const float* __restrict__ bl, float* __restrict__ out, int n) {
    int node = (int)((blockIdx.x * blockDim.x + threadIdx.x) >> 6);
    int lane = threadIdx.x & 63;
    if (node >= n) return;
    float v = agg[(size_t)node * 64 + lane] * Wl[lane];
    #pragma unroll
    for (int m = 32; m >= 1; m >>= 1) v += __shfl_xor(v, m);
    if (lane == 0) out[node] = 1.f / (1.f + expf(-(v + bl[0])));
}
template <int K>
__global__ __launch_bounds__(256) void gemm_rows4_k(
    const float* __restrict__ X, const float* __restrict__ W,
    float* __restrict__ Y, int n) {
    __shared__ float Ws[K * 64];
    for (int t = threadIdx.x; t < K * 64; t += blockDim.x) Ws[t] = W[t];
    __syncthreads();
    int wave   = (int)((blockIdx.x * blockDim.x + threadIdx.x) >> 6);
    int lane   = threadIdx.x & 63;
    int nwaves = (int)((gridDim.x * blockDim.x) >> 6);
    for (int r = wave; r < n; r += nwaves) {
        const float* xr = X + (size_t)r * K;
        float acc = 0.f;
        for (int k = 0; k < K; k += 4) {
            float4 a = *reinterpret_cast<const float4*>(xr + k);
            acc = fmaf(a.x, Ws[(k + 0) * 64 + lane], acc);
            acc = fmaf(a.y, Ws[(k + 1) * 64 + lane], acc);
            acc = fmaf(a.z, Ws[(k + 2) * 64 + lane], acc);
            acc = fmaf(a.w, Ws[(k + 3) * 64 + lane], acc);
        }
        Y[(size_t)r * 64 + lane] = acc;
    }
}

// ---------------------------------------------------------------------------

extern "C" void kernel_launch(void* const* d_in, const int* in_sizes, int n_in,
                              void* d_out, int out_size, void* d_ws, size_t ws_size,
                              hipStream_t stream) {
    const float* x  = (const float*)d_in[0];
    const int*   ei = (const int*)d_in[1];
    const float* W1 = (const float*)d_in[2];
    const float* b1 = (const float*)d_in[3];
    const float* W2 = (const float*)d_in[4];
    const float* b2 = (const float*)d_in[5];
    const float* Wl = (const float*)d_in[6];
    const float* bl = (const float*)d_in[7];
    float* out = (float*)d_out;

    const int n = in_sizes[0] / 128;      // 100000
    const int E = in_sizes[1] / 2;        // 1600000
    const int* src = ei;
    const int* dst = ei + E;

    const int B = 256;
    dim3 blk(B);
    auto align512 = [](size_t v) { return (v + 511) & ~(size_t)511; };

    // workspace layout (~46.5 MB)
    char* ws = (char*)d_ws;
    size_t off = 0;
    float*          dis     = (float*)(ws + off); off = align512(off + (size_t)n * 4);
    int*            hist    = (int*)  (ws + off); off = align512(off + (size_t)n * 4);
    int*            row_st  = (int*)  (ws + off); off = align512(off + (size_t)(n + 1) * 4);
    int*            cursor  = (int*)  (ws + off); off = align512(off + (size_t)n * 4);
    int*            bcur    = (int*)  (ws + off); off = align512(off + (size_t)NBMAX * 4);
    int*            csr_src = (int*)  (ws + off); off = align512(off + (size_t)E * 4);
    unsigned short* bufA16  = (unsigned short*)(ws + off); off = align512(off + (size_t)n * 64 * 2);
    unsigned short* h16     = (unsigned short*)(ws + off); off = align512(off + (size_t)n * 64 * 2);
    int2*           stage   = (int2*) (ws + off); off = align512(off + (size_t)E * 8);
    unsigned short* fw1     = (unsigned short*)(ws + off); off = align512(off + 8192 * 2);
    unsigned short* fw2     = (unsigned short*)(ws + off); off = align512(off + 4096 * 2);
    size_t need_csr = off;

    if (ws_size >= need_csr && (n & 15) == 0) {
        const int nbuckets = (n + 255) >> 8;

        wfrag_k<<<48, blk, 0, stream>>>(W1, W2, fw1, fw2);

        // ---- CSR build ----
        hipMemsetAsync(hist, 0, (size_t)n * 4, stream);
        hist_k<<<(E + B - 1) / B, blk, 0, stream>>>(dst, hist, E);
        dis_from_hist_k<<<(n + B - 1) / B, blk, 0, stream>>>(hist, dis, n);
        int nb = (n + SCAN_CHUNK - 1) / SCAN_CHUNK;
        int* bsum = csr_src + (size_t)E - nb - 1;   // scratch; consumed before csr writes
        scan_partial_k<<<nb, blk, 0, stream>>>(hist, bsum, n);
        scan_bsum_k<<<1, 64, 0, stream>>>(bsum, nb);
        scan_final_k<<<nb, blk, 0, stream>>>(hist, bsum, row_st, cursor, n);

        if (nbuckets <= NBMAX) {
            bucket_init_k<<<(nbuckets + B - 1) / B, blk, 0, stream>>>(row_st, bcur, nbuckets);
            partition_k<<<(E + EPB - 1) / EPB, blk, 0, stream>>>(src, dst, bcur, stage, E, nbuckets);
            place_k<<<(E + B - 1) / B, blk, 0, stream>>>(stage, cursor, csr_src, E);
        } else {
            scatter_k<<<(E + B - 1) / B, blk, 0, stream>>>(src, dst, cursor, csr_src, E);
        }

        int gemm_blocks = ((n >> 4) + 3) / 4;   // one wave per 16-row tile

        // ---- layer 1 ----
        mfma_gemm_k<128, false><<<gemm_blocks, blk, 0, stream>>>(x, fw1, dis, bufA16, n);
        gather_k<0><<<((size_t)n * 64 + B - 1) / B, blk, 0, stream>>>(
            row_st, csr_src, dis, bufA16, b1, Wl, bl, h16, n);

        // ---- layer 2 + head ----
        mfma_gemm_k<64, true><<<gemm_blocks, blk, 0, stream>>>(h16, fw2, dis, bufA16, n);
        gather_k<1><<<((size_t)n * 64 + B - 1) / B, blk, 0, stream>>>(
            row_st, csr_src, dis, bufA16, b2, Wl, bl, out, n);
    } else {
        // ---- fallback: atomic scatter, fp32 GEMM ----
        size_t o2 = 0;
        float* dis2 = (float*)(ws + o2); o2 = align512(o2 + (size_t)n * 4);
        float* bA   = (float*)(ws + o2); o2 += (size_t)n * 64 * 4;
        float* bB   = (float*)(ws + o2);

        deg_init_k<<<(n + B - 1) / B, blk, 0, stream>>>(dis2, n);
        deg_edges_k<<<(E + B - 1) / B, blk, 0, stream>>>(dst, dis2, E);
        dis_k<<<(n + B - 1) / B, blk, 0, stream>>>(dis2, n);

        gemm_rows4_k<128><<<2048, blk, 0, stream>>>(x, W1, bA, n);
        init_agg_k<<<((size_t)n * 64 + B - 1) / B, blk, 0, stream>>>(bA, dis2, b1, bB, n);
        agg_edges_k<<<(E + 3) / 4, blk, 0, stream>>>(src, dst, dis2, bA, bB, E);
        relu_k<<<((size_t)n * 64 + B - 1) / B, blk, 0, stream>>>(bB, (long long)n * 64);

        gemm_rows4_k<64><<<2048, blk, 0, stream>>>(bB, W2, bA, n);
        init_agg_k<<<((size_t)n * 64 + B - 1) / B, blk, 0, stream>>>(bA, dis2, b2, bB, n);
        agg_edges_k<<<(E + 3) / 4, blk, 0, stream>>>(src, dst, dis2, bA, bB, E);

        final_k<<<(n + 3) / 4, blk, 0, stream>>>(bB, Wl, bl, out, n);
    }
}

// Round 8
// 183.400 us; speedup vs baseline: 5.3879x; 1.4992x over previous
//
#include <hip/hip_runtime.h>
#include <hip/hip_bf16.h>

// ---------------------------------------------------------------------------
// EnhancedGNN: 2-layer GCN + linear head + sigmoid.
// R8: CSR build with no global atomics on hot paths:
//     bcount (LDS bucket hist) -> bscan (1-block scan) -> partition (stage
//     clustered by 256-node bucket) -> bucket_place (per-bucket LDS node hist
//     + scan + placement; also emits row_start and dis).
//     Gather (shfl-broadcast + 8 accs), MFMA GEMMs, bf16 features as R7.
// ---------------------------------------------------------------------------

#define EPB 4096      // edges per partition/count block
#define NBMAX 512     // max buckets (n/256) handled by the fast path

typedef __attribute__((ext_vector_type(8))) short bf16x8;
typedef __attribute__((ext_vector_type(4))) float f32x4;

__device__ __forceinline__ unsigned short f2b(float f) {   // fp32->bf16 RNE
    unsigned u = __builtin_bit_cast(unsigned, f);
    u += 0x7fffu + ((u >> 16) & 1u);
    return (unsigned short)(u >> 16);
}
__device__ __forceinline__ float b2f(unsigned short h) {
    unsigned u = (unsigned)h << 16;
    return __builtin_bit_cast(float, u);
}

// ---------------- CSR build ----------------

// Per-block LDS histogram over coarse buckets (node>>8), tiny global merge.
__global__ __launch_bounds__(256) void bcount_k(
    const int* __restrict__ dst, int* __restrict__ bucket_cnt, int E, int nbuckets) {
    __shared__ int lh[NBMAX];
    int t = threadIdx.x;
    for (int i = t; i < nbuckets; i += 256) lh[i] = 0;
    __syncthreads();
    int e0 = blockIdx.x * EPB;
    int cnt = min(EPB, E - e0);
    for (int i = t; i < cnt; i += 256) atomicAdd(&lh[dst[e0 + i] >> 8], 1);
    __syncthreads();
    for (int i = t; i < nbuckets; i += 256)
        if (lh[i]) atomicAdd(&bucket_cnt[i], lh[i]);
}

// Single-block exclusive scan of bucket counts -> bucket_base[0..nb], base[nb]=E.
__global__ __launch_bounds__(512) void bscan_k(
    const int* __restrict__ cnt, int* __restrict__ base, int nb) {
    __shared__ int s[512];
    int t = threadIdx.x;
    int v = (t < nb) ? cnt[t] : 0;
    s[t] = v; __syncthreads();
    #pragma unroll
    for (int off = 1; off < 512; off <<= 1) {
        int u = (t >= off) ? s[t - off] : 0;
        __syncthreads();
        s[t] += u;
        __syncthreads();
    }
    if (t < nb) base[t] = s[t] - v;
    if (t == nb - 1) base[nb] = s[t];
}

__global__ void bucket_init_k(const int* __restrict__ bucket_base, int* __restrict__ bucket_cur, int nbuckets) {
    int b = blockIdx.x * blockDim.x + threadIdx.x;
    if (b < nbuckets) bucket_cur[b] = bucket_base[b];
}

// Partition edges into dst-bucket-clustered staging (src,dst) pairs.
__global__ __launch_bounds__(256) void partition_k(
    const int* __restrict__ src, const int* __restrict__ dst,
    int* __restrict__ bucket_cur, int2* __restrict__ stage, int E, int nbuckets) {
    __shared__ int ls[EPB];
    __shared__ int ld[EPB];
    __shared__ int lhist[NBMAX];
    __shared__ int lbase[NBMAX];
    int e0 = blockIdx.x * EPB;
    int cnt = min(EPB, E - e0);
    int t = threadIdx.x;
    for (int i = t; i < cnt; i += 256) { ls[i] = src[e0 + i]; ld[i] = dst[e0 + i]; }
    for (int b = t; b < nbuckets; b += 256) lhist[b] = 0;
    __syncthreads();
    for (int i = t; i < cnt; i += 256) atomicAdd(&lhist[ld[i] >> 8], 1);
    __syncthreads();
    for (int b = t; b < nbuckets; b += 256) {
        int c = lhist[b];
        lbase[b] = (c > 0) ? atomicAdd(&bucket_cur[b], c) : 0;
        lhist[b] = 0;
    }
    __syncthreads();
    for (int i = t; i < cnt; i += 256) {
        int b  = ld[i] >> 8;
        int off = atomicAdd(&lhist[b], 1);
        stage[lbase[b] + off] = make_int2(ls[i], ld[i]);
    }
}

// One block per bucket: per-node LDS hist + scan -> row_start, dis, and
// csr placement with LDS cursors. All global writes confined to the bucket.
__global__ __launch_bounds__(256) void bucket_place_k(
    const int2* __restrict__ stage, const int* __restrict__ bucket_base,
    int* __restrict__ row_start, float* __restrict__ dis,
    int* __restrict__ csr_src, int n, int nbuckets) {
    __shared__ int lh[256];
    __shared__ int ss[256];
    __shared__ int lcur[256];
    int b = blockIdx.x;
    int t = threadIdx.x;
    int ebeg = bucket_base[b], eend = bucket_base[b + 1];
    int node0 = b << 8;

    lh[t] = 0;
    __syncthreads();
    for (int e = ebeg + t; e < eend; e += 256)
        atomicAdd(&lh[stage[e].y & 255], 1);
    __syncthreads();

    int cnt = lh[t];
    ss[t] = cnt;
    __syncthreads();
    #pragma unroll
    for (int off = 1; off < 256; off <<= 1) {
        int u = (t >= off) ? ss[t - off] : 0;
        __syncthreads();
        ss[t] += u;
        __syncthreads();
    }
    int excl = ss[t] - cnt;
    int node = node0 + t;
    if (node < n) {
        row_start[node] = ebeg + excl;
        dis[node] = rsqrtf((float)cnt + 1.0f);
    }
    lcur[t] = ebeg + excl;
    if (b == nbuckets - 1 && t == 0) row_start[n] = eend;
    __syncthreads();

    for (int e = ebeg + t; e < eend; e += 256) {
        int2 p = stage[e];
        int pos = atomicAdd(&lcur[p.y & 255], 1);
        csr_src[pos] = p.x;
    }
}

// ---------------- W -> MFMA B-fragment layout (bf16) ----------------
__global__ void wfrag_k(const float* __restrict__ W1, const float* __restrict__ W2,
                        unsigned short* __restrict__ fw1, unsigned short* __restrict__ fw2) {
    int gid = blockIdx.x * blockDim.x + threadIdx.x;
    if (gid < 8192) {
        int f = gid >> 9, rem = gid & 511;
        int l = rem >> 3, i = rem & 7;
        int ks = f >> 2, ct = f & 3;
        int k = ks * 32 + ((l >> 4) << 3) + i;
        int c = ct * 16 + (l & 15);
        fw1[gid] = f2b(W1[k * 64 + c]);
    } else if (gid < 8192 + 4096) {
        int g = gid - 8192;
        int f = g >> 9, rem = g & 511;
        int l = rem >> 3, i = rem & 7;
        int ks = f >> 2, ct = f & 3;
        int k = ks * 32 + ((l >> 4) << 3) + i;
        int c = ct * 16 + (l & 15);
        fw2[g] = f2b(W2[k * 64 + c]);
    }
}

// ---------------- MFMA GEMM: Y[r,:] = bf16( dis[r] * (X[r,:] @ W) ) ----------
template <int K, bool BF16IN>
__global__ __launch_bounds__(256) void mfma_gemm_k(
    const void* __restrict__ Xv, const unsigned short* __restrict__ FW,
    const float* __restrict__ dis, unsigned short* __restrict__ Y, int n) {
    constexpr int KS = K / 32;
    int wave   = (int)((blockIdx.x * blockDim.x + threadIdx.x) >> 6);
    int lane   = threadIdx.x & 63;
    int nwaves = (int)((gridDim.x * blockDim.x) >> 6);
    int ntiles = n >> 4;

    bf16x8 bfrag[KS][4];
    #pragma unroll
    for (int ks = 0; ks < KS; ++ks)
        #pragma unroll
        for (int ct = 0; ct < 4; ++ct)
            bfrag[ks][ct] = *reinterpret_cast<const bf16x8*>(FW + ((ks * 4 + ct) << 9) + (lane << 3));

    int rb = lane & 15;
    int kb = (lane >> 4) << 3;

    for (int tile = wave; tile < ntiles; tile += nwaves) {
        int row = (tile << 4) + rb;
        f32x4 acc[4];
        #pragma unroll
        for (int ct = 0; ct < 4; ++ct) acc[ct] = (f32x4){0.f, 0.f, 0.f, 0.f};

        #pragma unroll
        for (int ks = 0; ks < KS; ++ks) {
            bf16x8 af;
            if (BF16IN) {
                af = *reinterpret_cast<const bf16x8*>(
                    (const unsigned short*)Xv + (size_t)row * K + ks * 32 + kb);
            } else {
                const float* p = (const float*)Xv + (size_t)row * K + ks * 32 + kb;
                float4 u = *reinterpret_cast<const float4*>(p);
                float4 v = *reinterpret_cast<const float4*>(p + 4);
                af[0] = (short)f2b(u.x); af[1] = (short)f2b(u.y);
                af[2] = (short)f2b(u.z); af[3] = (short)f2b(u.w);
                af[4] = (short)f2b(v.x); af[5] = (short)f2b(v.y);
                af[6] = (short)f2b(v.z); af[7] = (short)f2b(v.w);
            }
            #pragma unroll
            for (int ct = 0; ct < 4; ++ct)
                acc[ct] = __builtin_amdgcn_mfma_f32_16x16x32_bf16(af, bfrag[ks][ct], acc[ct], 0, 0, 0);
        }

        int orow0 = (tile << 4) + ((lane >> 4) << 2);
        int ocol  = lane & 15;
        float dv0 = dis[orow0], dv1 = dis[orow0 + 1], dv2 = dis[orow0 + 2], dv3 = dis[orow0 + 3];
        #pragma unroll
        for (int ct = 0; ct < 4; ++ct) {
            Y[(size_t)(orow0 + 0) * 64 + ct * 16 + ocol] = f2b(acc[ct][0] * dv0);
            Y[(size_t)(orow0 + 1) * 64 + ct * 16 + ocol] = f2b(acc[ct][1] * dv1);
            Y[(size_t)(orow0 + 2) * 64 + ct * 16 + ocol] = f2b(acc[ct][2] * dv2);
            Y[(size_t)(orow0 + 3) * 64 + ct * 16 + ocol] = f2b(acc[ct][3] * dv3);
        }
    }

    for (int r = (ntiles << 4) + wave; r < n; r += nwaves) {
        float a = 0.f;
        int c = lane;
        for (int k = 0; k < K; ++k) {
            float xv = BF16IN ? b2f(((const unsigned short*)Xv)[(size_t)r * K + k])
                              : ((const float*)Xv)[(size_t)r * K + k];
            int f  = (k >> 5) * 4 + (c >> 4);
            int lf = (c & 15) + (((k & 31) >> 3) << 4);
            int i  = k & 7;
            a = fmaf(xv, b2f(FW[(f << 9) + (lf << 3) + i]), a);
        }
        Y[(size_t)r * 64 + c] = f2b(a * dis[r]);
    }
}

// ---------------- CSR gather aggregation (one wave per node) ----------------
template <int MODE>
__global__ __launch_bounds__(256) void gather_k(
    const int* __restrict__ row_start, const int* __restrict__ csr_src,
    const float* __restrict__ dis, const unsigned short* __restrict__ tp,
    const float* __restrict__ b, const float* __restrict__ Wl,
    const float* __restrict__ bl, void* __restrict__ outbuf, int n) {
    int node = (int)((blockIdx.x * blockDim.x + threadIdx.x) >> 6);
    int lane = threadIdx.x & 63;
    if (node >= n) return;
    int beg = row_start[node], end = row_start[node + 1];
    float dd = dis[node];
    float a0 = b2f(tp[(size_t)node * 64 + lane]);   // self term (pre-scaled)
    float a1 = 0.f, a2 = 0.f, a3 = 0.f, a4 = 0.f, a5 = 0.f, a6 = 0.f, a7 = 0.f;

    for (int base = beg; base < end; base += 64) {
        int rem = end - base;
        int cnt = rem < 64 ? rem : 64;
        int idx = (lane < cnt) ? csr_src[base + lane] : 0;   // one coalesced load / 64 edges
        int j = 0;
        for (; j + 8 <= cnt; j += 8) {
            int s0 = __shfl(idx, j + 0), s1 = __shfl(idx, j + 1);
            int s2 = __shfl(idx, j + 2), s3 = __shfl(idx, j + 3);
            int s4 = __shfl(idx, j + 4), s5 = __shfl(idx, j + 5);
            int s6 = __shfl(idx, j + 6), s7 = __shfl(idx, j + 7);
            a0 += b2f(tp[(size_t)s0 * 64 + lane]);
            a1 += b2f(tp[(size_t)s1 * 64 + lane]);
            a2 += b2f(tp[(size_t)s2 * 64 + lane]);
            a3 += b2f(tp[(size_t)s3 * 64 + lane]);
            a4 += b2f(tp[(size_t)s4 * 64 + lane]);
            a5 += b2f(tp[(size_t)s5 * 64 + lane]);
            a6 += b2f(tp[(size_t)s6 * 64 + lane]);
            a7 += b2f(tp[(size_t)s7 * 64 + lane]);
        }
        if (j + 4 <= cnt) {
            int s0 = __shfl(idx, j + 0), s1 = __shfl(idx, j + 1);
            int s2 = __shfl(idx, j + 2), s3 = __shfl(idx, j + 3);
            a0 += b2f(tp[(size_t)s0 * 64 + lane]);
            a1 += b2f(tp[(size_t)s1 * 64 + lane]);
            a2 += b2f(tp[(size_t)s2 * 64 + lane]);
            a3 += b2f(tp[(size_t)s3 * 64 + lane]);
            j += 4;
        }
        for (; j < cnt; ++j) {
            int s = __shfl(idx, j);
            a4 += b2f(tp[(size_t)s * 64 + lane]);
        }
    }

    float acc = ((a0 + a1) + (a2 + a3)) + ((a4 + a5) + (a6 + a7));
    float r = fmaf(dd, acc, b[lane]);

    if (MODE == 0) {
        ((unsigned short*)outbuf)[(size_t)node * 64 + lane] = f2b(fmaxf(r, 0.f));
    } else {
        float v = r * Wl[lane];
        #pragma unroll
        for (int m = 32; m >= 1; m >>= 1) v += __shfl_xor(v, m);
        if (lane == 0) ((float*)outbuf)[node] = 1.f / (1.f + expf(-(v + bl[0])));
    }
}

// ---------------- fallback kernels (only if ws too small / n%16 / nbuckets) ---

__global__ void relu_k(float* __restrict__ p, long long m) {
    long long i = (long long)blockIdx.x * blockDim.x + threadIdx.x;
    if (i < m) p[i] = fmaxf(p[i], 0.f);
}
__global__ void deg_init_k(float* __restrict__ deg, int n) {
    int i = blockIdx.x * blockDim.x + threadIdx.x;
    if (i < n) deg[i] = 1.0f;
}
__global__ void deg_edges_k(const int* __restrict__ dst, float* __restrict__ deg, int E) {
    int e = blockIdx.x * blockDim.x + threadIdx.x;
    if (e < E) atomicAdd(&deg[dst[e]], 1.0f);
}
__global__ void dis_k(float* __restrict__ deg, int n) {
    int i = blockIdx.x * blockDim.x + threadIdx.x;
    if (i < n) deg[i] = rsqrtf(deg[i]);
}
__global__ void init_agg_k(const float* __restrict__ t, const float* __restrict__ dis,
                           const float* __restrict__ b, float* __restrict__ agg, int n) {
    int idx = blockIdx.x * blockDim.x + threadIdx.x;
    if (idx >= n * 64) return;
    int i = idx >> 6, jj = idx & 63;
    float ds = dis[i];
    agg[idx] = ds * ds * t[idx] + b[jj];
}
__global__ __launch_bounds__(256) void agg_edges_k(
    const int* __restrict__ src, const int* __restrict__ dst,
    const float* __restrict__ dis, const float* __restrict__ t,
    float* __restrict__ agg, int E) {
    int e    = (int)((blockIdx.x * blockDim.x + threadIdx.x) >> 6);
    int lane = threadIdx.x & 63;
    if (e >= E) return;
    int s = src[e], d = dst[e];
    float w = dis[s] * dis[d];
    atomicAdd(&agg[(size_t)d * 64 + lane], w * t[(size_t)s * 64 + lane]);
}
__global__ __launch_bounds__(256) void final_k(
    const float* __restrict__ agg, const float* __restrict__ Wl,
    const float* __restrict__ bl, float* __restrict__ out, int n) {
    int node = (int)((blockIdx.x * blockDim.x + threadIdx.x) >> 6);
    int lane = threadIdx.x & 63;
    if (node >= n) return;
    float v = agg[(size_t)node * 64 + lane] * Wl[lane];
    #pragma unroll
    for (int m = 32; m >= 1; m >>= 1) v += __shfl_xor(v, m);
    if (lane == 0) out[node] = 1.f / (1.f + expf(-(v + bl[0])));
}
template <int K>
__global__ __launch_bounds__(256) void gemm_rows4_k(
    const float* __restrict__ X, const float* __restrict__ W,
    float* __restrict__ Y, int n) {
    __shared__ float Ws[K * 64];
    for (int t = threadIdx.x; t < K * 64; t += blockDim.x) Ws[t] = W[t];
    __syncthreads();
    int wave   = (int)((blockIdx.x * blockDim.x + threadIdx.x) >> 6);
    int lane   = threadIdx.x & 63;
    int nwaves = (int)((gridDim.x * blockDim.x) >> 6);
    for (int r = wave; r < n; r += nwaves) {
        const float* xr = X + (size_t)r * K;
        float acc = 0.f;
        for (int k = 0; k < K; k += 4) {
            float4 a = *reinterpret_cast<const float4*>(xr + k);
            acc = fmaf(a.x, Ws[(k + 0) * 64 + lane], acc);
            acc = fmaf(a.y, Ws[(k + 1) * 64 + lane], acc);
            acc = fmaf(a.z, Ws[(k + 2) * 64 + lane], acc);
            acc = fmaf(a.w, Ws[(k + 3) * 64 + lane], acc);
        }
        Y[(size_t)r * 64 + lane] = acc;
    }
}

// ---------------------------------------------------------------------------

extern "C" void kernel_launch(void* const* d_in, const int* in_sizes, int n_in,
                              void* d_out, int out_size, void* d_ws, size_t ws_size,
                              hipStream_t stream) {
    const float* x  = (const float*)d_in[0];
    const int*   ei = (const int*)d_in[1];
    const float* W1 = (const float*)d_in[2];
    const float* b1 = (const float*)d_in[3];
    const float* W2 = (const float*)d_in[4];
    const float* b2 = (const float*)d_in[5];
    const float* Wl = (const float*)d_in[6];
    const float* bl = (const float*)d_in[7];
    float* out = (float*)d_out;

    const int n = in_sizes[0] / 128;      // 100000
    const int E = in_sizes[1] / 2;        // 1600000
    const int* src = ei;
    const int* dst = ei + E;

    const int B = 256;
    dim3 blk(B);
    auto align512 = [](size_t v) { return (v + 511) & ~(size_t)511; };

    // workspace layout
    char* ws = (char*)d_ws;
    size_t off = 0;
    float*          dis     = (float*)(ws + off); off = align512(off + (size_t)n * 4);
    int*            row_st  = (int*)  (ws + off); off = align512(off + (size_t)(n + 1) * 4);
    int*            bcnt    = (int*)  (ws + off); off = align512(off + (size_t)(NBMAX + 1) * 4);
    int*            bbase   = (int*)  (ws + off); off = align512(off + (size_t)(NBMAX + 1) * 4);
    int*            bcur    = (int*)  (ws + off); off = align512(off + (size_t)NBMAX * 4);
    int*            csr_src = (int*)  (ws + off); off = align512(off + (size_t)E * 4);
    unsigned short* bufA16  = (unsigned short*)(ws + off); off = align512(off + (size_t)n * 64 * 2);
    unsigned short* h16     = (unsigned short*)(ws + off); off = align512(off + (size_t)n * 64 * 2);
    int2*           stage   = (int2*) (ws + off); off = align512(off + (size_t)E * 8);
    unsigned short* fw1     = (unsigned short*)(ws + off); off = align512(off + 8192 * 2);
    unsigned short* fw2     = (unsigned short*)(ws + off); off = align512(off + 4096 * 2);
    size_t need_csr = off;

    const int nbuckets = (n + 255) >> 8;
    const int nebl = (E + EPB - 1) / EPB;   // edge blocks

    if (ws_size >= need_csr && (n & 15) == 0 && nbuckets <= NBMAX) {
        // ---- W fragment packing (tiny) ----
        wfrag_k<<<48, blk, 0, stream>>>(W1, W2, fw1, fw2);

        // ---- CSR build (LDS-privatized, no hot global atomics) ----
        hipMemsetAsync(bcnt, 0, (size_t)(NBMAX + 1) * 4, stream);
        bcount_k<<<nebl, blk, 0, stream>>>(dst, bcnt, E, nbuckets);
        bscan_k<<<1, 512, 0, stream>>>(bcnt, bbase, nbuckets);
        bucket_init_k<<<(nbuckets + B - 1) / B, blk, 0, stream>>>(bbase, bcur, nbuckets);
        partition_k<<<nebl, blk, 0, stream>>>(src, dst, bcur, stage, E, nbuckets);
        bucket_place_k<<<nbuckets, blk, 0, stream>>>(stage, bbase, row_st, dis, csr_src, n, nbuckets);

        int gemm_blocks = ((n >> 4) + 3) / 4;   // one wave per 16-row tile

        // ---- layer 1 ----
        mfma_gemm_k<128, false><<<gemm_blocks, blk, 0, stream>>>(x, fw1, dis, bufA16, n);
        gather_k<0><<<((size_t)n * 64 + B - 1) / B, blk, 0, stream>>>(
            row_st, csr_src, dis, bufA16, b1, Wl, bl, h16, n);

        // ---- layer 2 + head ----
        mfma_gemm_k<64, true><<<gemm_blocks, blk, 0, stream>>>(h16, fw2, dis, bufA16, n);
        gather_k<1><<<((size_t)n * 64 + B - 1) / B, blk, 0, stream>>>(
            row_st, csr_src, dis, bufA16, b2, Wl, bl, out, n);
    } else {
        // ---- fallback: atomic scatter, fp32 GEMM ----
        size_t o2 = 0;
        float* dis2 = (float*)(ws + o2); o2 = align512(o2 + (size_t)n * 4);
        float* bA   = (float*)(ws + o2); o2 += (size_t)n * 64 * 4;
        float* bB   = (float*)(ws + o2);

        deg_init_k<<<(n + B - 1) / B, blk, 0, stream>>>(dis2, n);
        deg_edges_k<<<(E + B - 1) / B, blk, 0, stream>>>(dst, dis2, E);
        dis_k<<<(n + B - 1) / B, blk, 0, stream>>>(dis2, n);

        gemm_rows4_k<128><<<2048, blk, 0, stream>>>(x, W1, bA, n);
        init_agg_k<<<((size_t)n * 64 + B - 1) / B, blk, 0, stream>>>(bA, dis2, b1, bB, n);
        agg_edges_k<<<(E + 3) / 4, blk, 0, stream>>>(src, dst, dis2, bA, bB, E);
        relu_k<<<((size_t)n * 64 + B - 1) / B, blk, 0, stream>>>(bB, (long long)n * 64);

        gemm_rows4_k<64><<<2048, blk, 0, stream>>>(bB, W2, bA, n);
        init_agg_k<<<((size_t)n * 64 + B - 1) / B, blk, 0, stream>>>(bA, dis2, b2, bB, n);
        agg_edges_k<<<(E + 3) / 4, blk, 0, stream>>>(src, dst, dis2, bA, bB, E);

        final_k<<<(n + 3) / 4, blk, 0, stream>>>(bB, Wl, bl, out, n);
    }
}